// Round 2
// baseline (517.766 us; speedup 1.0000x reference)
//
#include <hip/hip_runtime.h>
#include <math.h>

// Problem constants
#define B_DIM 8
#define A_DIM 48
#define GF_DIM 256
#define S_DIM 4096
#define P_DIM 32
#define E_DIM 5
#define OHN 100           // sum(SIZES), SIZES = 5 x 20
#define XDIM 356          // OHN + GF
#define NBINS 65536
#define XS_STRIDE 360     // LDS x row stride (floats); 32*360*4 = 46080 B

// ---------------- wave helpers (wave64) ----------------
__device__ __forceinline__ float wave_sum(float v) {
#pragma unroll
    for (int o = 32; o; o >>= 1) v += __shfl_xor(v, o, 64);
    return v;
}
__device__ __forceinline__ float wave_max(float v) {
#pragma unroll
    for (int o = 32; o; o >>= 1) v = fmaxf(v, __shfl_xor(v, o, 64));
    return v;
}

__device__ __forceinline__ float therm_val(int j, float c0, float c1, float c2,
                                           float c3, float c4) {
    int e = j / 20;
    int pos = j - e * 20;
    float ce = (e == 0) ? c0 : (e == 1) ? c1 : (e == 2) ? c2 : (e == 3) ? c3 : c4;
    return ((float)pos < ce) ? 1.0f : 0.0f;
}

// async global->LDS, 16B per lane (dest = wave-uniform base + lane*16)
__device__ __forceinline__ void g2l16(float* lds, const float* g) {
    __builtin_amdgcn_global_load_lds(
        (const __attribute__((address_space(1))) void*)g,
        (__attribute__((address_space(3))) void*)lds,
        16, 0, 0);
}

// ---------------- K1: per-subset features -> x0 rows (356 f32) ----------------
__global__ __launch_bounds__(256) void k_features(
    const float* __restrict__ vert_feat,   // (B,48,256)
    const float* __restrict__ vert_mask,   // (B,48)
    const float* __restrict__ elem_oh,     // (B,48,5)
    const int*   __restrict__ subsets,     // (B,4096,48)
    float* __restrict__ xbuf)              // (32768, 356)
{
    __shared__ float4 vertm[A_DIM][GF_DIM / 4];
    __shared__ float  maskL[A_DIM];
    __shared__ int    eiL[A_DIM];

    const int tid  = threadIdx.x;
    const int lane = tid & 63;
    const int w    = tid >> 6;
    const int b    = blockIdx.x >> 9;
    const int s0   = (blockIdx.x & 511) * 8;

    if (tid < A_DIM) {
        maskL[tid] = vert_mask[b * A_DIM + tid];
        int ei = 0;
#pragma unroll
        for (int e = 0; e < E_DIM; ++e)
            if (elem_oh[(b * A_DIM + tid) * E_DIM + e] > 0.5f) ei = e;
        eiL[tid] = ei;
    }
    __syncthreads();

    const float4* vb = (const float4*)(vert_feat + (size_t)b * A_DIM * GF_DIM);
    for (int idx = tid; idx < A_DIM * (GF_DIM / 4); idx += 256) {
        float4 v = vb[idx];
        float mk = maskL[idx >> 6];
        v.x *= mk; v.y *= mk; v.z *= mk; v.w *= mk;
        vertm[idx >> 6][idx & 63] = v;
    }
    __syncthreads();

    const int   myei   = (lane < A_DIM) ? eiL[lane] : -1;
    const float mymask = (lane < A_DIM) ? maskL[lane] : 0.0f;

#pragma unroll
    for (int i = 0; i < 2; ++i) {
        const int s = s0 + w * 2 + i;
        const int* fp = subsets + ((size_t)b * S_DIM + s) * A_DIM;
        int myflag = (lane < A_DIM) ? fp[lane] : 0;
        float fcoef = (float)myflag * mymask;

        float c0, c1, c2, c3, c4;
        {
            unsigned long long m0 = __ballot(myflag != 0 && myei == 0);
            unsigned long long m1 = __ballot(myflag != 0 && myei == 1);
            unsigned long long m2 = __ballot(myflag != 0 && myei == 2);
            unsigned long long m3 = __ballot(myflag != 0 && myei == 3);
            unsigned long long m4 = __ballot(myflag != 0 && myei == 4);
            c0 = (float)__popcll(m0); c1 = (float)__popcll(m1);
            c2 = (float)__popcll(m2); c3 = (float)__popcll(m3);
            c4 = (float)__popcll(m4);
        }
        float ssize = wave_sum(fcoef) + 1e-4f;

        float4 acc = make_float4(0.f, 0.f, 0.f, 0.f);
        for (int a = 0; a < A_DIM; ++a) {
            float cf = __shfl(fcoef, a, 64);
            float4 vv = vertm[a][lane];
            acc.x = fmaf(cf, vv.x, acc.x);
            acc.y = fmaf(cf, vv.y, acc.y);
            acc.z = fmaf(cf, vv.z, acc.z);
            acc.w = fmaf(cf, vv.w, acc.w);
        }
        float inv = 1.0f / ssize;
        float4 mv = make_float4(acc.x * inv, acc.y * inv, acc.z * inv, acc.w * inv);

        float t = wave_sum(mv.x + mv.y + mv.z + mv.w);
        float m = t * (1.0f / 256.0f);
        float dx = mv.x - m, dy = mv.y - m, dz = mv.z - m, dw = mv.w - m;
        float q = wave_sum(dx * dx + dy * dy + dz * dz + dw * dw);
        float rs = 1.0f / sqrtf(q * (1.0f / 256.0f) + 1e-5f);

        float* xr = xbuf + ((size_t)b * S_DIM + s) * XDIM;
        xr[lane] = therm_val(lane, c0, c1, c2, c3, c4);
        if (lane < OHN - 64)
            xr[lane + 64] = therm_val(lane + 64, c0, c1, c2, c3, c4);
        *(float4*)(xr + OHN + lane * 4) =
            make_float4(dx * rs, dy * rs, dz * rs, dw * rs);
    }
}

// ---------------- fused MLP building blocks ----------------
// issue one W stage (R rows of 256 f32) into wb via async LDS-DMA
template <int R>
__device__ __forceinline__ void issue_stage(float* wb, const float* __restrict__ Wg,
                                            int tid) {
#pragma unroll
    for (int rd = 0; rd < R / 4; ++rd)          // 4 rows = 4096 B per round
        g2l16(wb + rd * 1024 + tid * 4, Wg + rd * 1024 + tid * 4);
}

// compute KR k-steps from wb against this wave's 8 x-rows
template <int KR>
__device__ __forceinline__ void compute_stage(const float* wb, const float* xsb,
                                              int ks, int c0, float acc[8][4]) {
#pragma unroll
    for (int k0 = 0; k0 < KR; k0 += 4) {
        float4 w0 = *(const float4*)(wb + (k0 + 0) * 256 + c0);
        float4 w1 = *(const float4*)(wb + (k0 + 1) * 256 + c0);
        float4 w2 = *(const float4*)(wb + (k0 + 2) * 256 + c0);
        float4 w3 = *(const float4*)(wb + (k0 + 3) * 256 + c0);
#pragma unroll
        for (int r = 0; r < 8; ++r) {
            float4 xv = *(const float4*)(xsb + r * XS_STRIDE + ks + k0);
            acc[r][0] = fmaf(xv.x, w0.x, acc[r][0]);
            acc[r][1] = fmaf(xv.x, w0.y, acc[r][1]);
            acc[r][2] = fmaf(xv.x, w0.z, acc[r][2]);
            acc[r][3] = fmaf(xv.x, w0.w, acc[r][3]);
            acc[r][0] = fmaf(xv.y, w1.x, acc[r][0]);
            acc[r][1] = fmaf(xv.y, w1.y, acc[r][1]);
            acc[r][2] = fmaf(xv.y, w1.z, acc[r][2]);
            acc[r][3] = fmaf(xv.y, w1.w, acc[r][3]);
            acc[r][0] = fmaf(xv.z, w2.x, acc[r][0]);
            acc[r][1] = fmaf(xv.z, w2.y, acc[r][1]);
            acc[r][2] = fmaf(xv.z, w2.z, acc[r][2]);
            acc[r][3] = fmaf(xv.z, w2.w, acc[r][3]);
            acc[r][0] = fmaf(xv.w, w3.x, acc[r][0]);
            acc[r][1] = fmaf(xv.w, w3.y, acc[r][1]);
            acc[r][2] = fmaf(xv.w, w3.z, acc[r][2]);
            acc[r][3] = fmaf(xv.w, w3.w, acc[r][3]);
        }
    }
}

// full layer: W (K,256) row-major, double-buffered staging through wbuf
template <int K>
__device__ __forceinline__ void gemm_layer(const float* __restrict__ Wg,
                                           float (*wbuf)[4096], const float* xsb,
                                           int tid, int c0, float acc[8][4]) {
    constexpr int NSF  = K / 16;                 // full stages
    constexpr int TAIL = K - NSF * 16;           // 0 or 4
    constexpr int NST  = NSF + (TAIL ? 1 : 0);
    constexpr int TR   = TAIL ? TAIL : 16;       // avoid <0> instantiation

    issue_stage<16>(wbuf[0], Wg, tid);
    int buf = 0;
    for (int s = 0; s < NST; ++s) {
        __syncthreads();                          // stage s resident in wbuf[buf]
        if (s + 1 < NST) {                        // prefetch s+1 (overlaps compute)
            const float* src = Wg + (s + 1) * 16 * 256;
            if (s + 1 < NSF) issue_stage<16>(wbuf[buf ^ 1], src, tid);
            else             issue_stage<TR>(wbuf[buf ^ 1], src, tid);
        }
        if (s < NSF) compute_stage<16>(wbuf[buf], xsb, s * 16, c0, acc);
        else         compute_stage<TR>(wbuf[buf], xsb, s * 16, c0, acc);
        buf ^= 1;
    }
    __syncthreads();   // protect wbuf against next layer's stage-0 issue
}

__device__ __forceinline__ void zero_acc(float acc[8][4]) {
#pragma unroll
    for (int r = 0; r < 8; ++r) {
        acc[r][0] = 0.f; acc[r][1] = 0.f; acc[r][2] = 0.f; acc[r][3] = 0.f;
    }
}

__device__ __forceinline__ void inorm_rows(float acc[8][4]) {
#pragma unroll
    for (int r = 0; r < 8; ++r) {
        float t = wave_sum(acc[r][0] + acc[r][1] + acc[r][2] + acc[r][3]);
        float m = t * (1.0f / 256.0f);
        float d0 = acc[r][0] - m, d1 = acc[r][1] - m;
        float d2 = acc[r][2] - m, d3 = acc[r][3] - m;
        float q = wave_sum(d0 * d0 + d1 * d1 + d2 * d2 + d3 * d3);
        float rs = 1.0f / sqrtf(q * (1.0f / 256.0f) + 1e-5f);
        acc[r][0] = d0 * rs; acc[r][1] = d1 * rs;
        acc[r][2] = d2 * rs; acc[r][3] = d3 * rs;
    }
}

// ---------------- fused MLP: combine+inorm, l1, l2a, l2b+inorm+score --------
__global__ __launch_bounds__(256, 2) void k_mlp_fused(
    const float* __restrict__ xbuf,
    const float* __restrict__ combine_W, const float* __restrict__ combine_b,
    const float* __restrict__ l1_W,  const float* __restrict__ l1_b,
    const float* __restrict__ l2a_W, const float* __restrict__ l2a_b,
    const float* __restrict__ l2b_W, const float* __restrict__ l2b_b,
    const float* __restrict__ score_W, const float* __restrict__ score_b,
    float* __restrict__ scores)
{
    __shared__ float xs[32 * XS_STRIDE];   // 46080 B
    __shared__ float wbuf[2][4096];        // 32768 B (2 x 16 rows x 256 f32)

    const int tid  = threadIdx.x;
    const int lane = tid & 63;
    const int wv   = tid >> 6;
    const int row0 = blockIdx.x * 32;
    const int r0   = wv * 8;               // wave owns rows r0..r0+7
    const int c0   = lane * 4;
    float* xsb = xs + r0 * XS_STRIDE;      // this wave's x rows

    // load x0 (356 cols per row) into LDS — each wave fills its own rows
#pragma unroll
    for (int r = 0; r < 8; ++r) {
        const float* src = xbuf + (size_t)(row0 + r0 + r) * XDIM;
        float* dst = xsb + r * XS_STRIDE;
        for (int j = lane; j < XDIM / 4; j += 64)
            *(float4*)(dst + 4 * j) = *(const float4*)(src + 4 * j);
    }

    float acc[8][4];

    // ---- L1: combine (K=356), relu + inorm ----
    zero_acc(acc);
    gemm_layer<356>(combine_W, wbuf, xsb, tid, c0, acc);
    {
        float4 bv = *(const float4*)(combine_b + c0);
#pragma unroll
        for (int r = 0; r < 8; ++r) {
            acc[r][0] = fmaxf(acc[r][0] + bv.x, 0.f);
            acc[r][1] = fmaxf(acc[r][1] + bv.y, 0.f);
            acc[r][2] = fmaxf(acc[r][2] + bv.z, 0.f);
            acc[r][3] = fmaxf(acc[r][3] + bv.w, 0.f);
        }
        inorm_rows(acc);
#pragma unroll
        for (int r = 0; r < 8; ++r)
            *(float4*)(xsb + r * XS_STRIDE + c0) =
                make_float4(acc[r][0], acc[r][1], acc[r][2], acc[r][3]);
    }

    // ---- L2: l1 (K=256), relu ----
    zero_acc(acc);
    gemm_layer<256>(l1_W, wbuf, xsb, tid, c0, acc);
    {
        float4 bv = *(const float4*)(l1_b + c0);
#pragma unroll
        for (int r = 0; r < 8; ++r) {
            acc[r][0] = fmaxf(acc[r][0] + bv.x, 0.f);
            acc[r][1] = fmaxf(acc[r][1] + bv.y, 0.f);
            acc[r][2] = fmaxf(acc[r][2] + bv.z, 0.f);
            acc[r][3] = fmaxf(acc[r][3] + bv.w, 0.f);
        }
#pragma unroll
        for (int r = 0; r < 8; ++r)
            *(float4*)(xsb + r * XS_STRIDE + c0) =
                make_float4(acc[r][0], acc[r][1], acc[r][2], acc[r][3]);
    }

    // ---- L3: l2a (K=256), leaky ----
    zero_acc(acc);
    gemm_layer<256>(l2a_W, wbuf, xsb, tid, c0, acc);
    {
        float4 bv = *(const float4*)(l2a_b + c0);
#pragma unroll
        for (int r = 0; r < 8; ++r) {
#pragma unroll
            for (int c = 0; c < 4; ++c) {
                float z = acc[r][c] + ((c == 0) ? bv.x : (c == 1) ? bv.y
                                        : (c == 2) ? bv.z : bv.w);
                acc[r][c] = (z > 0.f) ? z : 0.01f * z;
            }
        }
#pragma unroll
        for (int r = 0; r < 8; ++r)
            *(float4*)(xsb + r * XS_STRIDE + c0) =
                make_float4(acc[r][0], acc[r][1], acc[r][2], acc[r][3]);
    }

    // ---- L4: l2b (K=256), leaky->relu == relu, inorm, score ----
    zero_acc(acc);
    gemm_layer<256>(l2b_W, wbuf, xsb, tid, c0, acc);
    {
        float4 bv = *(const float4*)(l2b_b + c0);
#pragma unroll
        for (int r = 0; r < 8; ++r) {
            acc[r][0] = fmaxf(acc[r][0] + bv.x, 0.f);
            acc[r][1] = fmaxf(acc[r][1] + bv.y, 0.f);
            acc[r][2] = fmaxf(acc[r][2] + bv.z, 0.f);
            acc[r][3] = fmaxf(acc[r][3] + bv.w, 0.f);
        }
        inorm_rows(acc);
        float4 sv = *(const float4*)(score_W + c0);
        float sbv = score_b[0];
#pragma unroll
        for (int r = 0; r < 8; ++r) {
            float p = acc[r][0] * sv.x + acc[r][1] * sv.y +
                      acc[r][2] * sv.z + acc[r][3] * sv.w;
            p = wave_sum(p) + sbv;
            if (lane == r) scores[row0 + r0 + r] = p;
        }
    }
}

// ---------------- softmax over S=4096 per batch (in-place) ----------------
__global__ __launch_bounds__(256) void k_softmax(float* __restrict__ probs) {
    const int b   = blockIdx.x;
    const int tid = threadIdx.x;
    __shared__ float redA[4];
    __shared__ float redB[4];
    float* sp = probs + (size_t)b * S_DIM;

    float v[16];
    float mx = -INFINITY;
#pragma unroll
    for (int i = 0; i < 16; ++i) {
        v[i] = sp[tid + i * 256];
        mx = fmaxf(mx, v[i]);
    }
    mx = wave_max(mx);
    if ((tid & 63) == 0) redA[tid >> 6] = mx;
    __syncthreads();
    mx = fmaxf(fmaxf(redA[0], redA[1]), fmaxf(redA[2], redA[3]));

    float sum = 0.f;
#pragma unroll
    for (int i = 0; i < 16; ++i) {
        v[i] = expf(v[i] - mx);
        sum += v[i];
    }
    sum = wave_sum(sum);
    if ((tid & 63) == 0) redB[tid >> 6] = sum;
    __syncthreads();
    float tot = redB[0] + redB[1] + redB[2] + redB[3];
    float inv = 1.0f / tot;
#pragma unroll
    for (int i = 0; i < 16; ++i) sp[tid + i * 256] = v[i] * inv;
}

// ---------------- zero + scatter ----------------
__global__ __launch_bounds__(256) void k_zero(float* __restrict__ p, int n) {
    int i = blockIdx.x * 256 + threadIdx.x;
    if (i < n) p[i] = 0.0f;
}

__global__ __launch_bounds__(256) void k_scatter(
    const int*   __restrict__ mass_idx,
    const float* __restrict__ intensity,
    const float* __restrict__ probs,
    float* __restrict__ spect)
{
    int i  = blockIdx.x * 256 + threadIdx.x;
    int bs = i >> 5;
    int b  = i >> 17;
    float w = intensity[i] * probs[bs];
    unsafeAtomicAdd(spect + ((size_t)b << 16) + mass_idx[i], w);
}

// ---------------- launch ----------------
extern "C" void kernel_launch(void* const* d_in, const int* in_sizes, int n_in,
                              void* d_out, int out_size, void* d_ws, size_t ws_size,
                              hipStream_t stream) {
    const float* vert_feat = (const float*)d_in[0];
    const float* vert_mask = (const float*)d_in[1];
    const float* elem_oh   = (const float*)d_in[2];
    const int*   subsets   = (const int*)d_in[4];
    const int*   mass_idx  = (const int*)d_in[6];
    const float* intensity = (const float*)d_in[7];
    const float* combine_W = (const float*)d_in[8];
    const float* combine_b = (const float*)d_in[9];
    const float* l1_W      = (const float*)d_in[10];
    const float* l1_b      = (const float*)d_in[11];
    const float* l2a_W     = (const float*)d_in[12];
    const float* l2a_b     = (const float*)d_in[13];
    const float* l2b_W     = (const float*)d_in[14];
    const float* l2b_b     = (const float*)d_in[15];
    const float* score_W   = (const float*)d_in[16];
    const float* score_b   = (const float*)d_in[17];

    float* out   = (float*)d_out;
    float* spect = out;                          // B*NBINS
    float* probs = out + (size_t)B_DIM * NBINS;  // B*S (scores -> probs in place)
    float* xbuf  = (float*)d_ws;                 // 32768 x 356 f32

    k_features<<<4096, 256, 0, stream>>>(vert_feat, vert_mask, elem_oh, subsets, xbuf);
    k_mlp_fused<<<1024, 256, 0, stream>>>(
        xbuf, combine_W, combine_b, l1_W, l1_b, l2a_W, l2a_b, l2b_W, l2b_b,
        score_W, score_b, probs);
    k_softmax<<<B_DIM, 256, 0, stream>>>(probs);
    k_zero<<<(B_DIM * NBINS) / 256, 256, 0, stream>>>(spect, B_DIM * NBINS);
    k_scatter<<<(B_DIM * S_DIM * P_DIM) / 256, 256, 0, stream>>>(
        mass_idx, intensity, probs, spect);
}

// Round 3
// 295.829 us; speedup vs baseline: 1.7502x; 1.7502x over previous
//
#include <hip/hip_runtime.h>
#include <math.h>

// Problem constants
#define B_DIM 8
#define A_DIM 48
#define GF_DIM 256
#define S_DIM 4096
#define P_DIM 32
#define E_DIM 5
#define OHN 100
#define NBINS 65536

typedef __attribute__((ext_vector_type(8))) short short8v;
typedef __attribute__((ext_vector_type(4))) float float4v;

// ---------------- helpers ----------------
__device__ __forceinline__ float wave_sum(float v) {
#pragma unroll
    for (int o = 32; o; o >>= 1) v += __shfl_xor(v, o, 64);
    return v;
}
__device__ __forceinline__ float wave_max(float v) {
#pragma unroll
    for (int o = 32; o; o >>= 1) v = fmaxf(v, __shfl_xor(v, o, 64));
    return v;
}
__device__ __forceinline__ float quad16_sum(float v) {
    v += __shfl_xor(v, 1, 64); v += __shfl_xor(v, 2, 64);
    v += __shfl_xor(v, 4, 64); v += __shfl_xor(v, 8, 64);
    return v;
}
__device__ __forceinline__ unsigned short bf16_rn(float x) {
    unsigned int u = __float_as_uint(x);
    return (unsigned short)((u + 0x7FFFu + ((u >> 16) & 1u)) >> 16);
}
__device__ __forceinline__ float bf16_val(unsigned short h) {
    return __uint_as_float(((unsigned int)h) << 16);
}
__device__ __forceinline__ float therm_val(int j, float c0, float c1, float c2,
                                           float c3, float c4) {
    int e = j / 20;
    int pos = j - e * 20;
    float ce = (e == 0) ? c0 : (e == 1) ? c1 : (e == 2) ? c2 : (e == 3) ? c3 : c4;
    return ((float)pos < ce) ? 1.0f : 0.0f;
}
__device__ __forceinline__ void g2l16(float* lds, const float* g) {
    __builtin_amdgcn_global_load_lds(
        (const __attribute__((address_space(1))) void*)g,
        (__attribute__((address_space(3))) void*)lds,
        16, 0, 0);
}

// ---------------- W prep: split f32 -> (hi,lo) bf16 in B-frag stream order ---
// Stream: 36 chunks of 16384 shorts. Chunk c: [hi 8192][lo 8192];
// within half: i = nt*512 + lane*8 + j  <->  (k = kc*32 + (lane>>4)*8 + j,
// n = nt*16 + (lane&15)). Chunks 0..11: combine (k' reorder: therm 0..99 ->
// 0..99, pad 100..127 zero, normed -> 128..383); 12..19 l1; 20..27 l2a; 28..35 l2b.
__global__ __launch_bounds__(256) void k_wprep(
    const float* __restrict__ cW, const float* __restrict__ l1W,
    const float* __restrict__ l2aW, const float* __restrict__ l2bW,
    short* __restrict__ wp)
{
    int e = blockIdx.x * 256 + threadIdx.x;          // < 36*8192 = 294912
    int c = e >> 13;
    int i = e & 8191;
    int nt = i >> 9, lane = (i >> 3) & 63, j = i & 7;
    int krel = (lane >> 4) * 8 + j;
    int n = nt * 16 + (lane & 15);
    float val = 0.f;
    if (c < 12) {
        int kp = c * 32 + krel;
        if (kp < 100)       val = cW[kp * 256 + n];
        else if (kp >= 128) val = cW[(kp - 28) * 256 + n];
    } else {
        int L = (c - 12) >> 3;
        int kc = (c - 12) & 7;
        const float* W = (L == 0) ? l1W : (L == 1) ? l2aW : l2bW;
        val = W[(kc * 32 + krel) * 256 + n];
    }
    unsigned short h = bf16_rn(val);
    float lo = val - bf16_val(h);
    wp[c * 16384 + i]        = (short)h;
    wp[c * 16384 + 8192 + i] = (short)bf16_rn(lo);
}

// ---------------- K1: per-subset features -> x0 in A-frag hi/lo layout -------
// x0h: [fb 512][kc 12][mt 4][lane 64][j 8] bf16 ; x0l: same with kc 8 (kc-4).
__global__ __launch_bounds__(256) void k_features(
    const float* __restrict__ vert_feat, const float* __restrict__ vert_mask,
    const float* __restrict__ elem_oh, const int* __restrict__ subsets,
    short* __restrict__ x0h, short* __restrict__ x0l)
{
    __shared__ float4 vertm[A_DIM][GF_DIM / 4];
    __shared__ float  maskL[A_DIM];
    __shared__ int    eiL[A_DIM];

    const int tid  = threadIdx.x;
    const int lane = tid & 63;
    const int w    = tid >> 6;
    const int b    = blockIdx.x >> 9;
    const int s0   = (blockIdx.x & 511) * 8;

    if (tid < A_DIM) {
        maskL[tid] = vert_mask[b * A_DIM + tid];
        int ei = 0;
#pragma unroll
        for (int e = 0; e < E_DIM; ++e)
            if (elem_oh[(b * A_DIM + tid) * E_DIM + e] > 0.5f) ei = e;
        eiL[tid] = ei;
    }
    __syncthreads();

    const float4* vb = (const float4*)(vert_feat + (size_t)b * A_DIM * GF_DIM);
    for (int idx = tid; idx < A_DIM * (GF_DIM / 4); idx += 256) {
        float4 v = vb[idx];
        float mk = maskL[idx >> 6];
        v.x *= mk; v.y *= mk; v.z *= mk; v.w *= mk;
        vertm[idx >> 6][idx & 63] = v;
    }
    __syncthreads();

    const int   myei   = (lane < A_DIM) ? eiL[lane] : -1;
    const float mymask = (lane < A_DIM) ? maskL[lane] : 0.0f;

#pragma unroll
    for (int i = 0; i < 2; ++i) {
        const int s = s0 + w * 2 + i;
        const int* fp = subsets + ((size_t)b * S_DIM + s) * A_DIM;
        int myflag = (lane < A_DIM) ? fp[lane] : 0;
        float fcoef = (float)myflag * mymask;

        float c0, c1, c2, c3, c4;
        {
            unsigned long long m0 = __ballot(myflag != 0 && myei == 0);
            unsigned long long m1 = __ballot(myflag != 0 && myei == 1);
            unsigned long long m2 = __ballot(myflag != 0 && myei == 2);
            unsigned long long m3 = __ballot(myflag != 0 && myei == 3);
            unsigned long long m4 = __ballot(myflag != 0 && myei == 4);
            c0 = (float)__popcll(m0); c1 = (float)__popcll(m1);
            c2 = (float)__popcll(m2); c3 = (float)__popcll(m3);
            c4 = (float)__popcll(m4);
        }
        float ssize = wave_sum(fcoef) + 1e-4f;

        float4 acc = make_float4(0.f, 0.f, 0.f, 0.f);
        for (int a = 0; a < A_DIM; ++a) {
            float cf = __shfl(fcoef, a, 64);
            float4 vv = vertm[a][lane];
            acc.x = fmaf(cf, vv.x, acc.x);
            acc.y = fmaf(cf, vv.y, acc.y);
            acc.z = fmaf(cf, vv.z, acc.z);
            acc.w = fmaf(cf, vv.w, acc.w);
        }
        float inv = 1.0f / ssize;
        float4 mv = make_float4(acc.x * inv, acc.y * inv, acc.z * inv, acc.w * inv);

        float t = wave_sum(mv.x + mv.y + mv.z + mv.w);
        float m = t * (1.0f / 256.0f);
        float dx = mv.x - m, dy = mv.y - m, dz = mv.z - m, dw = mv.w - m;
        float q = wave_sum(dx * dx + dy * dy + dz * dz + dw * dw);
        float rs = 1.0f / sqrtf(q * (1.0f / 256.0f) + 1e-5f);

        // ---- frag-layout output ----
        const int row = b * S_DIM + s;
        const int fb  = row >> 6;
        const int mloc = row & 63;
        const int mt2 = mloc >> 4;
        const int m15 = mloc & 15;

        // thermometer (hi only, kc 0..3): lane handles k' = 2*lane, 2*lane+1
        {
            int kp = 2 * lane;
            int kc = lane >> 4;
            int qd = (kp & 31) >> 3;
            int j  = kp & 7;
            float t0 = (kp < 100)     ? therm_val(kp, c0, c1, c2, c3, c4) : 0.f;
            float t1 = (kp + 1 < 100) ? therm_val(kp + 1, c0, c1, c2, c3, c4) : 0.f;
            size_t elem = (((size_t)(fb * 12 + kc)) * 4 + mt2) * 512
                        + (qd * 16 + m15) * 8 + j;
            unsigned int wd = (unsigned int)bf16_rn(t0)
                            | ((unsigned int)bf16_rn(t1) << 16);
            ((unsigned int*)x0h)[elem >> 1] = wd;
        }
        // normed (kc 4..11): lane owns cols c = 4*lane..4*lane+3
        {
            float v0 = dx * rs, v1 = dy * rs, v2 = dz * rs, v3 = dw * rs;
            int kc = 4 + (lane >> 3);
            int qd = (lane & 7) >> 1;
            int j  = (lane & 1) * 4;
            size_t eh = (((size_t)(fb * 12 + kc)) * 4 + mt2) * 512
                      + (qd * 16 + m15) * 8 + j;
            unsigned short h0 = bf16_rn(v0), h1 = bf16_rn(v1),
                           h2 = bf16_rn(v2), h3 = bf16_rn(v3);
            uint2 wh; wh.x = (unsigned int)h0 | ((unsigned int)h1 << 16);
            wh.y = (unsigned int)h2 | ((unsigned int)h3 << 16);
            ((uint2*)x0h)[eh >> 2] = wh;
            unsigned short g0 = bf16_rn(v0 - bf16_val(h0)),
                           g1 = bf16_rn(v1 - bf16_val(h1)),
                           g2 = bf16_rn(v2 - bf16_val(h2)),
                           g3 = bf16_rn(v3 - bf16_val(h3));
            size_t el = (((size_t)(fb * 8 + (kc - 4))) * 4 + mt2) * 512
                      + (qd * 16 + m15) * 8 + j;
            uint2 wl; wl.x = (unsigned int)g0 | ((unsigned int)g1 << 16);
            wl.y = (unsigned int)g2 | ((unsigned int)g3 << 16);
            ((uint2*)x0l)[el >> 2] = wl;
        }
    }
}

// ---------------- fused MFMA MLP ----------------
__device__ __forceinline__ void issue_chunk(short* dst, const short* src, int tid) {
    const float* s = (const float*)src;
    float* d = (float*)dst;
#pragma unroll
    for (int i = 0; i < 4; ++i)
        g2l16(d + i * 2048 + tid * 4, s + i * 2048 + tid * 4);
}

// One GEMM layer with fused epilogue.
// NKC: K chunks of 32. LO0: first kc that has an x_lo chunk (lo index = kc-LO0).
// ACT: 0 relu, 1 leaky.
template <int NKC, int LO0, int ACT, bool NORM, bool SCORE>
__device__ __forceinline__ void layer_pass(
    short* xAh, short* xAl, short* wst0, short* wst1, float (*ps)[64],
    const short* __restrict__ wstream, const float* __restrict__ bias,
    const float* __restrict__ sW, const float* __restrict__ sb,
    float* __restrict__ scores, int R0)
{
    const int tid  = threadIdx.x;
    const int lane = tid & 63;
    const int w    = tid >> 6;
    const int wm   = w >> 2;     // 0..1  (m half)
    const int wn   = w & 3;      // 0..3  (n quarter)
    const int quad = lane >> 4;
    const int col  = lane & 15;

    float4v acc[2][4];
#pragma unroll
    for (int mi = 0; mi < 2; ++mi)
#pragma unroll
        for (int nt = 0; nt < 4; ++nt) acc[mi][nt] = (float4v){0.f, 0.f, 0.f, 0.f};

    issue_chunk(wst0, wstream, tid);
    for (int kc = 0; kc < NKC; ++kc) {
        __syncthreads();                               // chunk kc resident
        if (kc + 1 < NKC)
            issue_chunk(((kc + 1) & 1) ? wst1 : wst0,
                        wstream + (kc + 1) * 16384, tid);
        const short* wsl = (kc & 1) ? wst1 : wst0;

        short8v ah[2], al[2];
        const bool hlo = (kc >= LO0);
#pragma unroll
        for (int mi = 0; mi < 2; ++mi) {
            ah[mi] = *(const short8v*)(xAh + (((kc) * 4 + wm * 2 + mi) * 64 + lane) * 8);
            if (hlo)
                al[mi] = *(const short8v*)(xAl + (((kc - LO0) * 4 + wm * 2 + mi) * 64 + lane) * 8);
        }
        short8v bh[4], bl[4];
#pragma unroll
        for (int nt = 0; nt < 4; ++nt) {
            bh[nt] = *(const short8v*)(wsl + ((wn * 4 + nt) * 64 + lane) * 8);
            bl[nt] = *(const short8v*)(wsl + 8192 + ((wn * 4 + nt) * 64 + lane) * 8);
        }
#pragma unroll
        for (int mi = 0; mi < 2; ++mi)
#pragma unroll
            for (int nt = 0; nt < 4; ++nt) {
                acc[mi][nt] = __builtin_amdgcn_mfma_f32_16x16x32_bf16(
                    ah[mi], bh[nt], acc[mi][nt], 0, 0, 0);
                acc[mi][nt] = __builtin_amdgcn_mfma_f32_16x16x32_bf16(
                    ah[mi], bl[nt], acc[mi][nt], 0, 0, 0);
                if (hlo)
                    acc[mi][nt] = __builtin_amdgcn_mfma_f32_16x16x32_bf16(
                        al[mi], bh[nt], acc[mi][nt], 0, 0, 0);
            }
    }

    // ---- epilogue: bias + activation ----
    float bcol[4];
#pragma unroll
    for (int nt = 0; nt < 4; ++nt) bcol[nt] = bias[wn * 64 + nt * 16 + col];
#pragma unroll
    for (int mi = 0; mi < 2; ++mi)
#pragma unroll
        for (int nt = 0; nt < 4; ++nt)
#pragma unroll
            for (int r = 0; r < 4; ++r) {
                float z = acc[mi][nt][r] + bcol[nt];
                if (ACT == 0) z = fmaxf(z, 0.f);
                else          z = (z > 0.f) ? z : 0.01f * z;
                acc[mi][nt][r] = z;
            }

    __syncthreads();   // all xA/wst reads of this layer complete

    if (NORM) {
        float rsum[2][4];
#pragma unroll
        for (int mi = 0; mi < 2; ++mi)
#pragma unroll
            for (int r = 0; r < 4; ++r)
                rsum[mi][r] = quad16_sum(acc[mi][0][r] + acc[mi][1][r] +
                                         acc[mi][2][r] + acc[mi][3][r]);
        if (col == 0) {
#pragma unroll
            for (int mi = 0; mi < 2; ++mi)
#pragma unroll
                for (int r = 0; r < 4; ++r)
                    ps[wn][wm * 32 + mi * 16 + quad * 4 + r] = rsum[mi][r];
        }
        __syncthreads();
        float mu[2][4];
#pragma unroll
        for (int mi = 0; mi < 2; ++mi)
#pragma unroll
            for (int r = 0; r < 4; ++r) {
                int m = wm * 32 + mi * 16 + quad * 4 + r;
                mu[mi][r] = (ps[0][m] + ps[1][m] + ps[2][m] + ps[3][m]) * (1.f / 256.f);
            }
        __syncthreads();
#pragma unroll
        for (int mi = 0; mi < 2; ++mi)
#pragma unroll
            for (int nt = 0; nt < 4; ++nt)
#pragma unroll
                for (int r = 0; r < 4; ++r) acc[mi][nt][r] -= mu[mi][r];
        float qs[2][4];
#pragma unroll
        for (int mi = 0; mi < 2; ++mi)
#pragma unroll
            for (int r = 0; r < 4; ++r) {
                float q = acc[mi][0][r] * acc[mi][0][r] + acc[mi][1][r] * acc[mi][1][r]
                        + acc[mi][2][r] * acc[mi][2][r] + acc[mi][3][r] * acc[mi][3][r];
                qs[mi][r] = quad16_sum(q);
            }
        if (col == 0) {
#pragma unroll
            for (int mi = 0; mi < 2; ++mi)
#pragma unroll
                for (int r = 0; r < 4; ++r)
                    ps[wn][wm * 32 + mi * 16 + quad * 4 + r] = qs[mi][r];
        }
        __syncthreads();
#pragma unroll
        for (int mi = 0; mi < 2; ++mi)
#pragma unroll
            for (int r = 0; r < 4; ++r) {
                int m = wm * 32 + mi * 16 + quad * 4 + r;
                float vq = (ps[0][m] + ps[1][m] + ps[2][m] + ps[3][m]) * (1.f / 256.f);
                float rs = 1.0f / sqrtf(vq + 1e-5f);
#pragma unroll
                for (int nt = 0; nt < 4; ++nt) acc[mi][nt][r] *= rs;
            }
    }

    if (SCORE) {
        float sv[4];
#pragma unroll
        for (int nt = 0; nt < 4; ++nt) sv[nt] = sW[wn * 64 + nt * 16 + col];
        float psu[2][4];
#pragma unroll
        for (int mi = 0; mi < 2; ++mi)
#pragma unroll
            for (int r = 0; r < 4; ++r) {
                float p = acc[mi][0][r] * sv[0] + acc[mi][1][r] * sv[1]
                        + acc[mi][2][r] * sv[2] + acc[mi][3][r] * sv[3];
                psu[mi][r] = quad16_sum(p);
            }
        __syncthreads();
        if (col == 0) {
#pragma unroll
            for (int mi = 0; mi < 2; ++mi)
#pragma unroll
                for (int r = 0; r < 4; ++r)
                    ps[wn][wm * 32 + mi * 16 + quad * 4 + r] = psu[mi][r];
        }
        __syncthreads();
        if (wn == 0 && col == 0) {
            float sb0 = sb[0];
#pragma unroll
            for (int mi = 0; mi < 2; ++mi)
#pragma unroll
                for (int r = 0; r < 4; ++r) {
                    int m = wm * 32 + mi * 16 + quad * 4 + r;
                    scores[R0 + m] = ps[0][m] + ps[1][m] + ps[2][m] + ps[3][m] + sb0;
                }
        }
    } else {
        // writeback hi/lo into xA (next layer A-frag layout, LO0=0).
        // Paired lanes: even col writes packed hi (j0, j0+1); odd writes packed lo.
        const int mt2b = wm * 2;
#pragma unroll
        for (int mi = 0; mi < 2; ++mi) {
#pragma unroll
            for (int nt = 0; nt < 4; ++nt) {
                int n  = wn * 64 + nt * 16 + col;
                int n0 = n & ~1;
                int kc2 = n0 >> 5, q2 = (n0 & 31) >> 3, j0 = n0 & 7;
#pragma unroll
                for (int r = 0; r < 4; ++r) {
                    float v  = acc[mi][nt][r];
                    float pv = __shfl_xor(v, 1, 64);
                    int m15 = quad * 4 + r;
                    int rowidx = (kc2 * 4 + mt2b + mi) * 64 + q2 * 16 + m15;
                    if ((col & 1) == 0) {
                        unsigned int wd = (unsigned int)bf16_rn(v)
                                        | ((unsigned int)bf16_rn(pv) << 16);
                        ((unsigned int*)xAh)[rowidx * 4 + (j0 >> 1)] = wd;
                    } else {
                        float ls = v  - bf16_val(bf16_rn(v));
                        float lp = pv - bf16_val(bf16_rn(pv));
                        unsigned int wd = (unsigned int)bf16_rn(lp)
                                        | ((unsigned int)bf16_rn(ls) << 16);
                        ((unsigned int*)xAl)[rowidx * 4 + (j0 >> 1)] = wd;
                    }
                }
            }
        }
    }
}

__global__ __launch_bounds__(512, 2) void k_mlp_mfma(
    const short* __restrict__ wprep,
    const short* __restrict__ x0h, const short* __restrict__ x0l,
    const float* __restrict__ cb,  const float* __restrict__ l1b,
    const float* __restrict__ l2ab, const float* __restrict__ l2bb,
    const float* __restrict__ sW,  const float* __restrict__ sb,
    float* __restrict__ scores)
{
    __shared__ short xAh[12 * 4 * 64 * 8];   // 48 KB
    __shared__ short xAl[8 * 4 * 64 * 8];    // 32 KB
    __shared__ short wst[2][16384];          // 64 KB
    __shared__ float ps[4][64];              // 1 KB

    const int tid = threadIdx.x;
    const int fb  = blockIdx.x;
    const int R0  = fb * 64;

    // stage x0 fragments (async; drained by first layer barrier)
    {
        const float* sh = (const float*)(x0h + (size_t)fb * 24576);
#pragma unroll
        for (int i = 0; i < 6; ++i)
            g2l16((float*)xAh + i * 2048 + tid * 4, sh + i * 2048 + tid * 4);
        const float* sl = (const float*)(x0l + (size_t)fb * 16384);
#pragma unroll
        for (int i = 0; i < 4; ++i)
            g2l16((float*)xAl + i * 2048 + tid * 4, sl + i * 2048 + tid * 4);
    }

    layer_pass<12, 4, 0, true,  false>(xAh, xAl, wst[0], wst[1], ps,
        wprep +  0 * 16384, cb,   nullptr, nullptr, nullptr, R0);
    layer_pass< 8, 0, 0, false, false>(xAh, xAl, wst[0], wst[1], ps,
        wprep + 12 * 16384, l1b,  nullptr, nullptr, nullptr, R0);
    layer_pass< 8, 0, 1, false, false>(xAh, xAl, wst[0], wst[1], ps,
        wprep + 20 * 16384, l2ab, nullptr, nullptr, nullptr, R0);
    layer_pass< 8, 0, 0, true,  true >(xAh, xAl, wst[0], wst[1], ps,
        wprep + 28 * 16384, l2bb, sW, sb, scores, R0);
}

// ---------------- softmax / zero / scatter (unchanged) ----------------
__global__ __launch_bounds__(256) void k_softmax(float* __restrict__ probs) {
    const int b   = blockIdx.x;
    const int tid = threadIdx.x;
    __shared__ float redA[4];
    __shared__ float redB[4];
    float* sp = probs + (size_t)b * S_DIM;

    float v[16];
    float mx = -INFINITY;
#pragma unroll
    for (int i = 0; i < 16; ++i) {
        v[i] = sp[tid + i * 256];
        mx = fmaxf(mx, v[i]);
    }
    mx = wave_max(mx);
    if ((tid & 63) == 0) redA[tid >> 6] = mx;
    __syncthreads();
    mx = fmaxf(fmaxf(redA[0], redA[1]), fmaxf(redA[2], redA[3]));

    float sum = 0.f;
#pragma unroll
    for (int i = 0; i < 16; ++i) {
        v[i] = expf(v[i] - mx);
        sum += v[i];
    }
    sum = wave_sum(sum);
    if ((tid & 63) == 0) redB[tid >> 6] = sum;
    __syncthreads();
    float tot = redB[0] + redB[1] + redB[2] + redB[3];
    float inv = 1.0f / tot;
#pragma unroll
    for (int i = 0; i < 16; ++i) sp[tid + i * 256] = v[i] * inv;
}

__global__ __launch_bounds__(256) void k_zero(float* __restrict__ p, int n) {
    int i = blockIdx.x * 256 + threadIdx.x;
    if (i < n) p[i] = 0.0f;
}

__global__ __launch_bounds__(256) void k_scatter(
    const int*   __restrict__ mass_idx,
    const float* __restrict__ intensity,
    const float* __restrict__ probs,
    float* __restrict__ spect)
{
    int i  = blockIdx.x * 256 + threadIdx.x;
    int bs = i >> 5;
    int b  = i >> 17;
    float w = intensity[i] * probs[bs];
    unsafeAtomicAdd(spect + ((size_t)b << 16) + mass_idx[i], w);
}

// ---------------- launch ----------------
extern "C" void kernel_launch(void* const* d_in, const int* in_sizes, int n_in,
                              void* d_out, int out_size, void* d_ws, size_t ws_size,
                              hipStream_t stream) {
    const float* vert_feat = (const float*)d_in[0];
    const float* vert_mask = (const float*)d_in[1];
    const float* elem_oh   = (const float*)d_in[2];
    const int*   subsets   = (const int*)d_in[4];
    const int*   mass_idx  = (const int*)d_in[6];
    const float* intensity = (const float*)d_in[7];
    const float* combine_W = (const float*)d_in[8];
    const float* combine_b = (const float*)d_in[9];
    const float* l1_W      = (const float*)d_in[10];
    const float* l1_b      = (const float*)d_in[11];
    const float* l2a_W     = (const float*)d_in[12];
    const float* l2a_b     = (const float*)d_in[13];
    const float* l2b_W     = (const float*)d_in[14];
    const float* l2b_b     = (const float*)d_in[15];
    const float* score_W   = (const float*)d_in[16];
    const float* score_b   = (const float*)d_in[17];

    float* out   = (float*)d_out;
    float* spect = out;                           // B*NBINS
    float* probs = out + (size_t)B_DIM * NBINS;   // B*S (scores -> probs in place)

    short* wprep = (short*)d_ws;                  // 36*16384 shorts = 1.125 MB
    short* x0h   = wprep + 36 * 16384;            // 512*24576 shorts = 24 MB
    short* x0l   = x0h + (size_t)512 * 24576;     // 512*16384 shorts = 16 MB

    k_wprep<<<1152, 256, 0, stream>>>(combine_W, l1_W, l2a_W, l2b_W, wprep);
    k_features<<<4096, 256, 0, stream>>>(vert_feat, vert_mask, elem_oh, subsets,
                                         x0h, x0l);
    k_mlp_mfma<<<512, 512, 0, stream>>>(wprep, x0h, x0l,
        combine_b, l1_b, l2a_b, l2b_b, score_W, score_b, probs);
    k_softmax<<<B_DIM, 256, 0, stream>>>(probs);
    k_zero<<<(B_DIM * NBINS) / 256, 256, 0, stream>>>(spect, B_DIM * NBINS);
    k_scatter<<<(B_DIM * S_DIM * P_DIM) / 256, 256, 0, stream>>>(
        mass_idx, intensity, probs, spect);
}

// Round 4
// 286.147 us; speedup vs baseline: 1.8094x; 1.0338x over previous
//
#include <hip/hip_runtime.h>
#include <math.h>

// Problem constants
#define B_DIM 8
#define A_DIM 48
#define GF_DIM 256
#define S_DIM 4096
#define P_DIM 32
#define E_DIM 5
#define OHN 100
#define NBINS 65536

typedef __attribute__((ext_vector_type(8))) short short8v;
typedef __attribute__((ext_vector_type(4))) float float4v;

// ---------------- helpers ----------------
__device__ __forceinline__ float wave_sum(float v) {
#pragma unroll
    for (int o = 32; o; o >>= 1) v += __shfl_xor(v, o, 64);
    return v;
}
__device__ __forceinline__ float wave_max(float v) {
#pragma unroll
    for (int o = 32; o; o >>= 1) v = fmaxf(v, __shfl_xor(v, o, 64));
    return v;
}
__device__ __forceinline__ float quad16_sum(float v) {
    v += __shfl_xor(v, 1, 64); v += __shfl_xor(v, 2, 64);
    v += __shfl_xor(v, 4, 64); v += __shfl_xor(v, 8, 64);
    return v;
}
__device__ __forceinline__ unsigned short bf16_rn(float x) {
    unsigned int u = __float_as_uint(x);
    return (unsigned short)((u + 0x7FFFu + ((u >> 16) & 1u)) >> 16);
}
__device__ __forceinline__ float bf16_val(unsigned short h) {
    return __uint_as_float(((unsigned int)h) << 16);
}

// ---------------- W prep: f32 -> (hi,lo) bf16, B-frag stream ----------------
// 36 chunks of 16384 shorts (32 KB). Chunk c, frag_id = wn*4 + hl*2 + nt
// (wn 0..7 wave n-slice, hl 0=hi 1=lo, nt 0..1), frag = 512 shorts:
// element (lane, j) = W[k = c_rel*32 + (lane>>4)*8 + j][n = wn*32+nt*16+(lane&15)].
// Chunks 0..11 combine (k' map: therm 0..99 -> 0..99, 100..127 zero pad,
// normed -> 128..383); 12..19 l1; 20..27 l2a; 28..35 l2b.
__global__ __launch_bounds__(256) void k_wprep(
    const float* __restrict__ cW, const float* __restrict__ l1W,
    const float* __restrict__ l2aW, const float* __restrict__ l2bW,
    short* __restrict__ wp)
{
    int e = blockIdx.x * 256 + threadIdx.x;   // < 36*8192 = 294912
    int c = e >> 13;
    int i = e & 8191;                         // ((wn*2+nt)*64 + lane)*8 + j
    int j    = i & 7;
    int lane = (i >> 3) & 63;
    int nt   = (i >> 9) & 1;
    int wn   = i >> 10;
    int krel = (lane >> 4) * 8 + j;
    int n    = wn * 32 + nt * 16 + (lane & 15);
    float val = 0.f;
    if (c < 12) {
        int kp = c * 32 + krel;
        if (kp < 100)       val = cW[kp * 256 + n];
        else if (kp >= 128) val = cW[(kp - 28) * 256 + n];
    } else {
        int L  = (c - 12) >> 3;
        int kc = (c - 12) & 7;
        const float* W = (L == 0) ? l1W : (L == 1) ? l2aW : l2bW;
        val = W[(kc * 32 + krel) * 256 + n];
    }
    unsigned short h = bf16_rn(val);
    float lo = val - bf16_val(h);
    int base = c * 16384 + (i & 511);         // i&511 = lane*8+j
    wp[base + (wn * 4 + nt) * 512]     = (short)h;
    wp[base + (wn * 4 + 2 + nt) * 512] = (short)bf16_rn(lo);
}

// ---------------- mega kernel: features + transpose + 4-layer MFMA MLP ------
// LDS layout (bytes):
//   0      .. 49152  : xAh (24576 shorts)  | phase1/2: vertm float4[48][64]
//   49152  .. 115712 : xf32 (64 rows x 260 f32)
//   115712 .. 148480 : xAl (16384 shorts)
//   148480 .. 150528 : ps  float[8][64]
//   150528 .. 151808 : cnt float[64][5]
//   151808 .. 152000 : maskL float[48]
//   152000 .. 152192 : eiL int[48]
#define OFF_XF   49152
#define OFF_XAL  115712
#define OFF_PS   148480
#define OFF_CNT  150528
#define OFF_MASK 151808
#define OFF_EI   152000

__device__ __forceinline__ float4v mfma_bf16(short8v a, short8v b, float4v c) {
    return __builtin_amdgcn_mfma_f32_16x16x32_bf16(a, b, c, 0, 0, 0);
}

// One GEMM layer, barrier-free K loop. W from global (double-buffered regs).
template <int NKC, int LO0, int ACT, bool NORM, bool SCORE>
__device__ __forceinline__ void layer_pass(
    short* xAh, short* xAl, float (*ps)[64],
    const short* __restrict__ wstream, const float* __restrict__ bias,
    const float* __restrict__ sW, const float* __restrict__ sb,
    float* __restrict__ scores, int R0)
{
    const int tid  = threadIdx.x;
    const int lane = tid & 63;
    const int wn   = tid >> 6;
    const int quad = lane >> 4;
    const int col  = lane & 15;
    const short* wbase = wstream + wn * 2048 + lane * 8;

    float4v acc[4][2];
#pragma unroll
    for (int mi = 0; mi < 4; ++mi)
#pragma unroll
        for (int nt = 0; nt < 2; ++nt) acc[mi][nt] = (float4v){0.f, 0.f, 0.f, 0.f};

    short8v bh[2][2], bl[2][2];
    bh[0][0] = *(const short8v*)(wbase);
    bh[0][1] = *(const short8v*)(wbase + 512);
    bl[0][0] = *(const short8v*)(wbase + 1024);
    bl[0][1] = *(const short8v*)(wbase + 1536);

#pragma unroll
    for (int kc = 0; kc < NKC; ++kc) {
        const int cur = kc & 1;
        if (kc + 1 < NKC) {
            const short* p = wbase + (kc + 1) * 16384;
            bh[cur ^ 1][0] = *(const short8v*)(p);
            bh[cur ^ 1][1] = *(const short8v*)(p + 512);
            bl[cur ^ 1][0] = *(const short8v*)(p + 1024);
            bl[cur ^ 1][1] = *(const short8v*)(p + 1536);
        }
        short8v ah[4], al[4];
#pragma unroll
        for (int mi = 0; mi < 4; ++mi)
            ah[mi] = *(const short8v*)(xAh + ((kc * 4 + mi) * 64 + lane) * 8);
        const bool hlo = (kc >= LO0);
        if (hlo) {
#pragma unroll
            for (int mi = 0; mi < 4; ++mi)
                al[mi] = *(const short8v*)(xAl + (((kc - LO0) * 4 + mi) * 64 + lane) * 8);
        }
#pragma unroll
        for (int mi = 0; mi < 4; ++mi)
#pragma unroll
            for (int nt = 0; nt < 2; ++nt) {
                acc[mi][nt] = mfma_bf16(ah[mi], bh[cur][nt], acc[mi][nt]);
                acc[mi][nt] = mfma_bf16(ah[mi], bl[cur][nt], acc[mi][nt]);
                if (hlo)
                    acc[mi][nt] = mfma_bf16(al[mi], bh[cur][nt], acc[mi][nt]);
            }
    }

    // bias + activation
    float bc0 = bias[wn * 32 + col];
    float bc1 = bias[wn * 32 + 16 + col];
#pragma unroll
    for (int mi = 0; mi < 4; ++mi)
#pragma unroll
        for (int r = 0; r < 4; ++r) {
            float z0 = acc[mi][0][r] + bc0;
            float z1 = acc[mi][1][r] + bc1;
            if (ACT == 0) { z0 = fmaxf(z0, 0.f); z1 = fmaxf(z1, 0.f); }
            else { z0 = (z0 > 0.f) ? z0 : 0.01f * z0; z1 = (z1 > 0.f) ? z1 : 0.01f * z1; }
            acc[mi][0][r] = z0; acc[mi][1][r] = z1;
        }

    __syncthreads();   // all xA reads of this layer done; ps free

    if (NORM) {
        float rsum[4][4];
#pragma unroll
        for (int mi = 0; mi < 4; ++mi)
#pragma unroll
            for (int r = 0; r < 4; ++r)
                rsum[mi][r] = quad16_sum(acc[mi][0][r] + acc[mi][1][r]);
        if (col == 0) {
#pragma unroll
            for (int mi = 0; mi < 4; ++mi)
#pragma unroll
                for (int r = 0; r < 4; ++r)
                    ps[wn][mi * 16 + quad * 4 + r] = rsum[mi][r];
        }
        __syncthreads();
        float mu[4][4];
#pragma unroll
        for (int mi = 0; mi < 4; ++mi)
#pragma unroll
            for (int r = 0; r < 4; ++r) {
                int m = mi * 16 + quad * 4 + r;
                float s = 0.f;
#pragma unroll
                for (int w = 0; w < 8; ++w) s += ps[w][m];
                mu[mi][r] = s * (1.f / 256.f);
            }
        __syncthreads();
        float qs[4][4];
#pragma unroll
        for (int mi = 0; mi < 4; ++mi)
#pragma unroll
            for (int r = 0; r < 4; ++r) {
                acc[mi][0][r] -= mu[mi][r];
                acc[mi][1][r] -= mu[mi][r];
                float q = acc[mi][0][r] * acc[mi][0][r]
                        + acc[mi][1][r] * acc[mi][1][r];
                qs[mi][r] = quad16_sum(q);
            }
        if (col == 0) {
#pragma unroll
            for (int mi = 0; mi < 4; ++mi)
#pragma unroll
                for (int r = 0; r < 4; ++r)
                    ps[wn][mi * 16 + quad * 4 + r] = qs[mi][r];
        }
        __syncthreads();
#pragma unroll
        for (int mi = 0; mi < 4; ++mi)
#pragma unroll
            for (int r = 0; r < 4; ++r) {
                int m = mi * 16 + quad * 4 + r;
                float s = 0.f;
#pragma unroll
                for (int w = 0; w < 8; ++w) s += ps[w][m];
                float rsf = 1.0f / sqrtf(s * (1.f / 256.f) + 1e-5f);
                acc[mi][0][r] *= rsf;
                acc[mi][1][r] *= rsf;
            }
    }

    if (SCORE) {
        __syncthreads();   // ps var-reads done before reuse
        float sv0 = sW[wn * 32 + col];
        float sv1 = sW[wn * 32 + 16 + col];
        float psu[4][4];
#pragma unroll
        for (int mi = 0; mi < 4; ++mi)
#pragma unroll
            for (int r = 0; r < 4; ++r)
                psu[mi][r] = quad16_sum(acc[mi][0][r] * sv0 + acc[mi][1][r] * sv1);
        if (col == 0) {
#pragma unroll
            for (int mi = 0; mi < 4; ++mi)
#pragma unroll
                for (int r = 0; r < 4; ++r)
                    ps[wn][mi * 16 + quad * 4 + r] = psu[mi][r];
        }
        __syncthreads();
        if (tid < 64) {
            float s = sb[0];
#pragma unroll
            for (int w = 0; w < 8; ++w) s += ps[w][tid];
            scores[R0 + tid] = s;
        }
    } else {
        // writeback to next layer's A-frag layout; wave wn owns kc2 = wn.
#pragma unroll
        for (int mi = 0; mi < 4; ++mi)
#pragma unroll
            for (int nt = 0; nt < 2; ++nt) {
                int nn0 = (wn * 32 + nt * 16 + col) & ~1;
                int q2  = (nn0 & 31) >> 3;
                int j0  = nn0 & 7;
#pragma unroll
                for (int r = 0; r < 4; ++r) {
                    float v  = acc[mi][nt][r];
                    float pv = __shfl_xor(v, 1, 64);
                    int m15 = quad * 4 + r;
                    int rowidx = (wn * 4 + mi) * 64 + q2 * 16 + m15;
                    if ((col & 1) == 0) {
                        unsigned int wd = (unsigned int)bf16_rn(v)
                                        | ((unsigned int)bf16_rn(pv) << 16);
                        ((unsigned int*)xAh)[rowidx * 4 + (j0 >> 1)] = wd;
                    } else {
                        float ls = v  - bf16_val(bf16_rn(v));
                        float lp = pv - bf16_val(bf16_rn(pv));
                        unsigned int wd = (unsigned int)bf16_rn(lp)
                                        | ((unsigned int)bf16_rn(ls) << 16);
                        ((unsigned int*)xAl)[rowidx * 4 + (j0 >> 1)] = wd;
                    }
                }
            }
        __syncthreads();
    }
}

__global__ __launch_bounds__(512, 2) void k_mega(
    const float* __restrict__ vert_feat, const float* __restrict__ vert_mask,
    const float* __restrict__ elem_oh, const int* __restrict__ subsets,
    const short* __restrict__ wprep,
    const float* __restrict__ cb,  const float* __restrict__ l1b,
    const float* __restrict__ l2ab, const float* __restrict__ l2bb,
    const float* __restrict__ sW,  const float* __restrict__ sb,
    float* __restrict__ scores)
{
    __shared__ __align__(16) char smem[152192];
    short*  xAh   = (short*)smem;
    float*  xf    = (float*)(smem + OFF_XF);
    short*  xAl   = (short*)(smem + OFF_XAL);
    float (*ps)[64] = (float(*)[64])(smem + OFF_PS);
    float (*cnt)[5] = (float(*)[5])(smem + OFF_CNT);
    float*  maskL = (float*)(smem + OFF_MASK);
    int*    eiL   = (int*)(smem + OFF_EI);
    float4* vertm = (float4*)smem;          // [48][64], reused as xAh later

    const int tid  = threadIdx.x;
    const int lane = tid & 63;
    const int wn   = tid >> 6;
    const int fb   = blockIdx.x;            // 0..511
    const int b    = fb >> 6;
    const int R0   = fb * 64;

    // ---- phase 0: masks / element indices ----
    if (tid < A_DIM) {
        maskL[tid] = vert_mask[b * A_DIM + tid];
        int ei = 0;
#pragma unroll
        for (int e = 0; e < E_DIM; ++e)
            if (elem_oh[(b * A_DIM + tid) * E_DIM + e] > 0.5f) ei = e;
        eiL[tid] = ei;
    }
    __syncthreads();

    // ---- phase 1: stage masked vert (48x256 f32 = 48 KB) ----
    {
        const float4* vb = (const float4*)(vert_feat + (size_t)b * A_DIM * GF_DIM);
        for (int idx = tid; idx < A_DIM * 64; idx += 512) {
            float4 v = vb[idx];
            float mk = maskL[idx >> 6];
            v.x *= mk; v.y *= mk; v.z *= mk; v.w *= mk;
            vertm[idx] = v;
        }
    }
    __syncthreads();

    // ---- phase 2: per-subset features -> xf32 rows + counts ----
    {
        const float mymask = (lane < A_DIM) ? maskL[lane] : 0.f;
        const int   myei   = (lane < A_DIM) ? eiL[lane]   : -1;
#pragma unroll
        for (int i = 0; i < 8; ++i) {
            const int r = wn * 8 + i;
            const int* fp = subsets + ((size_t)fb * 64 + r) * A_DIM;
            int myflag = (lane < A_DIM) ? fp[lane] : 0;
            float fcoef = (float)myflag * mymask;

            float c0, c1, c2, c3, c4;
            {
                unsigned long long m0 = __ballot(myflag != 0 && myei == 0);
                unsigned long long m1 = __ballot(myflag != 0 && myei == 1);
                unsigned long long m2 = __ballot(myflag != 0 && myei == 2);
                unsigned long long m3 = __ballot(myflag != 0 && myei == 3);
                unsigned long long m4 = __ballot(myflag != 0 && myei == 4);
                c0 = (float)__popcll(m0); c1 = (float)__popcll(m1);
                c2 = (float)__popcll(m2); c3 = (float)__popcll(m3);
                c4 = (float)__popcll(m4);
            }
            float ssize = wave_sum(fcoef) + 1e-4f;

            float4 acc = make_float4(0.f, 0.f, 0.f, 0.f);
            for (int a = 0; a < A_DIM; ++a) {
                float cf = __shfl(fcoef, a, 64);
                float4 vv = vertm[a * 64 + lane];
                acc.x = fmaf(cf, vv.x, acc.x);
                acc.y = fmaf(cf, vv.y, acc.y);
                acc.z = fmaf(cf, vv.z, acc.z);
                acc.w = fmaf(cf, vv.w, acc.w);
            }
            float inv = 1.0f / ssize;
            float4 mv = make_float4(acc.x * inv, acc.y * inv,
                                    acc.z * inv, acc.w * inv);
            float t = wave_sum(mv.x + mv.y + mv.z + mv.w);
            float m = t * (1.0f / 256.0f);
            float dx = mv.x - m, dy = mv.y - m, dz = mv.z - m, dw = mv.w - m;
            float q = wave_sum(dx * dx + dy * dy + dz * dz + dw * dw);
            float rs = 1.0f / sqrtf(q * (1.0f / 256.0f) + 1e-5f);

            *(float4*)(xf + r * 260 + lane * 4) =
                make_float4(dx * rs, dy * rs, dz * rs, dw * rs);
            if (lane == 0) {
                cnt[r][0] = c0; cnt[r][1] = c1; cnt[r][2] = c2;
                cnt[r][3] = c3; cnt[r][4] = c4;
            }
        }
    }
    __syncthreads();   // xf/cnt ready; vertm dead

    // ---- phase 3: build A-frags (therm gen + f32->hi/lo transpose) ----
    {
#pragma unroll
        for (int g0 = 0; g0 < 6; ++g0) {
            int g  = tid + g0 * 512;        // 0..3071 hi groups
            int lt = g & 63;
            int t2 = g >> 6;                // kc*4 + mi
            int kc = t2 >> 2, mi = t2 & 3;
            int m  = mi * 16 + (lt & 15);
            int kb = (lt >> 4) * 8;
            if (kc < 4) {
                short8v hv;
#pragma unroll
                for (int j = 0; j < 8; ++j) {
                    int kp = kc * 32 + kb + j;
                    float val = 0.f;
                    if (kp < 100) {
                        int e = kp / 20;
                        val = ((float)(kp - e * 20) < cnt[m][e]) ? 1.0f : 0.0f;
                    }
                    hv[j] = (short)bf16_rn(val);
                }
                *(short8v*)(xAh + g * 8) = hv;
            } else {
                const float* src = xf + m * 260 + (kc - 4) * 32 + kb;
                float4 f0 = *(const float4*)(src);
                float4 f1 = *(const float4*)(src + 4);
                float fv[8] = {f0.x, f0.y, f0.z, f0.w, f1.x, f1.y, f1.z, f1.w};
                short8v hv, lv;
#pragma unroll
                for (int j = 0; j < 8; ++j) {
                    unsigned short h = bf16_rn(fv[j]);
                    hv[j] = (short)h;
                    lv[j] = (short)bf16_rn(fv[j] - bf16_val(h));
                }
                *(short8v*)(xAh + g * 8) = hv;
                *(short8v*)(xAl + (g - 1024) * 8) = lv;
            }
        }
    }
    __syncthreads();

    // ---- phase 4: the 4 layers ----
    layer_pass<12, 4, 0, true,  false>(xAh, xAl, ps, wprep,
        cb, nullptr, nullptr, nullptr, R0);
    layer_pass< 8, 0, 0, false, false>(xAh, xAl, ps, wprep + 12 * 16384,
        l1b, nullptr, nullptr, nullptr, R0);
    layer_pass< 8, 0, 1, false, false>(xAh, xAl, ps, wprep + 20 * 16384,
        l2ab, nullptr, nullptr, nullptr, R0);
    layer_pass< 8, 0, 0, true,  true >(xAh, xAl, ps, wprep + 28 * 16384,
        l2bb, sW, sb, scores, R0);
}

// ---------------- softmax / zero / scatter ----------------
__global__ __launch_bounds__(256) void k_softmax(float* __restrict__ probs) {
    const int b   = blockIdx.x;
    const int tid = threadIdx.x;
    __shared__ float redA[4];
    __shared__ float redB[4];
    float* sp = probs + (size_t)b * S_DIM;

    float v[16];
    float mx = -INFINITY;
#pragma unroll
    for (int i = 0; i < 16; ++i) {
        v[i] = sp[tid + i * 256];
        mx = fmaxf(mx, v[i]);
    }
    mx = wave_max(mx);
    if ((tid & 63) == 0) redA[tid >> 6] = mx;
    __syncthreads();
    mx = fmaxf(fmaxf(redA[0], redA[1]), fmaxf(redA[2], redA[3]));

    float sum = 0.f;
#pragma unroll
    for (int i = 0; i < 16; ++i) {
        v[i] = expf(v[i] - mx);
        sum += v[i];
    }
    sum = wave_sum(sum);
    if ((tid & 63) == 0) redB[tid >> 6] = sum;
    __syncthreads();
    float tot = redB[0] + redB[1] + redB[2] + redB[3];
    float inv = 1.0f / tot;
#pragma unroll
    for (int i = 0; i < 16; ++i) sp[tid + i * 256] = v[i] * inv;
}

__global__ __launch_bounds__(256) void k_zero(float* __restrict__ p, int n) {
    int i = blockIdx.x * 256 + threadIdx.x;
    if (i < n) p[i] = 0.0f;
}

__global__ __launch_bounds__(256) void k_scatter(
    const int*   __restrict__ mass_idx,
    const float* __restrict__ intensity,
    const float* __restrict__ probs,
    float* __restrict__ spect)
{
    int i  = blockIdx.x * 256 + threadIdx.x;
    int bs = i >> 5;
    int b  = i >> 17;
    float w = intensity[i] * probs[bs];
    unsafeAtomicAdd(spect + ((size_t)b << 16) + mass_idx[i], w);
}

// ---------------- launch ----------------
extern "C" void kernel_launch(void* const* d_in, const int* in_sizes, int n_in,
                              void* d_out, int out_size, void* d_ws, size_t ws_size,
                              hipStream_t stream) {
    const float* vert_feat = (const float*)d_in[0];
    const float* vert_mask = (const float*)d_in[1];
    const float* elem_oh   = (const float*)d_in[2];
    const int*   subsets   = (const int*)d_in[4];
    const int*   mass_idx  = (const int*)d_in[6];
    const float* intensity = (const float*)d_in[7];
    const float* combine_W = (const float*)d_in[8];
    const float* combine_b = (const float*)d_in[9];
    const float* l1_W      = (const float*)d_in[10];
    const float* l1_b      = (const float*)d_in[11];
    const float* l2a_W     = (const float*)d_in[12];
    const float* l2a_b     = (const float*)d_in[13];
    const float* l2b_W     = (const float*)d_in[14];
    const float* l2b_b     = (const float*)d_in[15];
    const float* score_W   = (const float*)d_in[16];
    const float* score_b   = (const float*)d_in[17];

    float* out   = (float*)d_out;
    float* spect = out;                           // B*NBINS
    float* probs = out + (size_t)B_DIM * NBINS;   // B*S (scores -> probs in place)
    short* wprep = (short*)d_ws;                  // 36*16384 shorts = 1.125 MB

    k_wprep<<<1152, 256, 0, stream>>>(combine_W, l1_W, l2a_W, l2b_W, wprep);
    k_mega<<<512, 512, 0, stream>>>(vert_feat, vert_mask, elem_oh, subsets,
        wprep, combine_b, l1_b, l2a_b, l2b_b, score_W, score_b, probs);
    k_softmax<<<B_DIM, 256, 0, stream>>>(probs);
    k_zero<<<(B_DIM * NBINS) / 256, 256, 0, stream>>>(spect, B_DIM * NBINS);
    k_scatter<<<(B_DIM * S_DIM * P_DIM) / 256, 256, 0, stream>>>(
        mass_idx, intensity, probs, spect);
}

// Round 5
// 284.639 us; speedup vs baseline: 1.8190x; 1.0053x over previous
//
#include <hip/hip_runtime.h>
#include <math.h>

// Problem constants
#define B_DIM 8
#define A_DIM 48
#define GF_DIM 256
#define S_DIM 4096
#define P_DIM 32
#define E_DIM 5
#define OHN 100
#define NBINS 65536
#define XF_STRIDE 268      // x0 row stride in f32: 256 normed + 5 counts + pad

typedef __attribute__((ext_vector_type(8))) short short8v;
typedef __attribute__((ext_vector_type(4))) float float4v;

// ---------------- helpers ----------------
__device__ __forceinline__ float wave_sum(float v) {
#pragma unroll
    for (int o = 32; o; o >>= 1) v += __shfl_xor(v, o, 64);
    return v;
}
__device__ __forceinline__ float wave_max(float v) {
#pragma unroll
    for (int o = 32; o; o >>= 1) v = fmaxf(v, __shfl_xor(v, o, 64));
    return v;
}
__device__ __forceinline__ float quad16_sum(float v) {
    v += __shfl_xor(v, 1, 64); v += __shfl_xor(v, 2, 64);
    v += __shfl_xor(v, 4, 64); v += __shfl_xor(v, 8, 64);
    return v;
}
__device__ __forceinline__ unsigned short bf16_rn(float x) {
    unsigned int u = __float_as_uint(x);
    return (unsigned short)((u + 0x7FFFu + ((u >> 16) & 1u)) >> 16);
}
__device__ __forceinline__ float bf16_val(unsigned short h) {
    return __uint_as_float(((unsigned int)h) << 16);
}

// ---------------- W prep: f32 -> (hi,lo) bf16, B-frag stream ----------------
// 36 chunks of 16384 shorts. Chunk c, frag_id = wn*4 + hl*2 + nt; frag 512 shorts:
// (lane,j) = W[k = c_rel*32 + (lane>>4)*8 + j][n = wn*32 + nt*16 + (lane&15)].
// Chunks 0..11 combine (therm k' 0..99, pad 100..127, normed -> 128..383);
// 12..19 l1; 20..27 l2a; 28..35 l2b.
__global__ __launch_bounds__(256) void k_wprep(
    const float* __restrict__ cW, const float* __restrict__ l1W,
    const float* __restrict__ l2aW, const float* __restrict__ l2bW,
    short* __restrict__ wp)
{
    int e = blockIdx.x * 256 + threadIdx.x;   // < 36*8192
    int c = e >> 13;
    int i = e & 8191;
    int j    = i & 7;
    int lane = (i >> 3) & 63;
    int nt   = (i >> 9) & 1;
    int wn   = i >> 10;
    int krel = (lane >> 4) * 8 + j;
    int n    = wn * 32 + nt * 16 + (lane & 15);
    float val = 0.f;
    if (c < 12) {
        int kp = c * 32 + krel;
        if (kp < 100)       val = cW[kp * 256 + n];
        else if (kp >= 128) val = cW[(kp - 28) * 256 + n];
    } else {
        int L  = (c - 12) >> 3;
        int kc = (c - 12) & 7;
        const float* W = (L == 0) ? l1W : (L == 1) ? l2aW : l2bW;
        val = W[(kc * 32 + krel) * 256 + n];
    }
    unsigned short h = bf16_rn(val);
    float lo = val - bf16_val(h);
    int base = c * 16384 + (i & 511);
    wp[base + (wn * 4 + nt) * 512]     = (short)h;
    wp[base + (wn * 4 + 2 + nt) * 512] = (short)bf16_rn(lo);
}

// ---------------- K1: features -> x0 rows (256 normed f32 + 5 counts) -------
__global__ __launch_bounds__(256) void k_features(
    const float* __restrict__ vert_feat, const float* __restrict__ vert_mask,
    const float* __restrict__ elem_oh, const int* __restrict__ subsets,
    float* __restrict__ x0)
{
    __shared__ float4 vertm[A_DIM][GF_DIM / 4];
    __shared__ float  maskL[A_DIM];
    __shared__ int    eiL[A_DIM];

    const int tid  = threadIdx.x;
    const int lane = tid & 63;
    const int w    = tid >> 6;
    const int b    = blockIdx.x >> 9;
    const int s0   = (blockIdx.x & 511) * 8;

    if (tid < A_DIM) {
        maskL[tid] = vert_mask[b * A_DIM + tid];
        int ei = 0;
#pragma unroll
        for (int e = 0; e < E_DIM; ++e)
            if (elem_oh[(b * A_DIM + tid) * E_DIM + e] > 0.5f) ei = e;
        eiL[tid] = ei;
    }
    __syncthreads();

    const float4* vb = (const float4*)(vert_feat + (size_t)b * A_DIM * GF_DIM);
    for (int idx = tid; idx < A_DIM * (GF_DIM / 4); idx += 256) {
        float4 v = vb[idx];
        float mk = maskL[idx >> 6];
        v.x *= mk; v.y *= mk; v.z *= mk; v.w *= mk;
        vertm[idx >> 6][idx & 63] = v;
    }
    __syncthreads();

    const int   myei   = (lane < A_DIM) ? eiL[lane] : -1;
    const float mymask = (lane < A_DIM) ? maskL[lane] : 0.0f;

#pragma unroll
    for (int i = 0; i < 2; ++i) {
        const int s = s0 + w * 2 + i;
        const int* fp = subsets + ((size_t)b * S_DIM + s) * A_DIM;
        int myflag = (lane < A_DIM) ? fp[lane] : 0;
        float fcoef = (float)myflag * mymask;

        float c0, c1, c2, c3, c4;
        {
            unsigned long long m0 = __ballot(myflag != 0 && myei == 0);
            unsigned long long m1 = __ballot(myflag != 0 && myei == 1);
            unsigned long long m2 = __ballot(myflag != 0 && myei == 2);
            unsigned long long m3 = __ballot(myflag != 0 && myei == 3);
            unsigned long long m4 = __ballot(myflag != 0 && myei == 4);
            c0 = (float)__popcll(m0); c1 = (float)__popcll(m1);
            c2 = (float)__popcll(m2); c3 = (float)__popcll(m3);
            c4 = (float)__popcll(m4);
        }
        float ssize = wave_sum(fcoef) + 1e-4f;

        float4 acc = make_float4(0.f, 0.f, 0.f, 0.f);
        for (int a = 0; a < A_DIM; ++a) {
            float cf = __shfl(fcoef, a, 64);
            float4 vv = vertm[a][lane];
            acc.x = fmaf(cf, vv.x, acc.x);
            acc.y = fmaf(cf, vv.y, acc.y);
            acc.z = fmaf(cf, vv.z, acc.z);
            acc.w = fmaf(cf, vv.w, acc.w);
        }
        float inv = 1.0f / ssize;
        float4 mv = make_float4(acc.x * inv, acc.y * inv, acc.z * inv, acc.w * inv);

        float t = wave_sum(mv.x + mv.y + mv.z + mv.w);
        float m = t * (1.0f / 256.0f);
        float dx = mv.x - m, dy = mv.y - m, dz = mv.z - m, dw = mv.w - m;
        float q = wave_sum(dx * dx + dy * dy + dz * dz + dw * dw);
        float rs = 1.0f / sqrtf(q * (1.0f / 256.0f) + 1e-5f);

        float* xr = x0 + (size_t)(b * S_DIM + s) * XF_STRIDE;
        *(float4*)(xr + lane * 4) = make_float4(dx * rs, dy * rs, dz * rs, dw * rs);
        if (lane < E_DIM)
            xr[256 + lane] = (lane == 0) ? c0 : (lane == 1) ? c1
                           : (lane == 2) ? c2 : (lane == 3) ? c3 : c4;
    }
}

// ---------------- MLP kernel: M=32/block, 2 blocks/CU ----------------
// LDS: xAh 24576 B | xf 34304 B | xAl 16384 B | ps 1024 B = 76288 B
#define OFF_XF  24576
#define OFF_XAL 58880
#define OFF_PS  75264

__device__ __forceinline__ float4v mfma_bf16(short8v a, short8v b, float4v c) {
    return __builtin_amdgcn_mfma_f32_16x16x32_bf16(a, b, c, 0, 0, 0);
}

// One GEMM layer, barrier-free K loop; W slice in regs (depth-2 prefetch).
template <int NKC, int LO0, int ACT, bool NORM, bool SCORE>
__device__ __forceinline__ void layer_pass(
    short* xAh, short* xAl, float (*ps)[32],
    const short* __restrict__ wstream, const float* __restrict__ bias,
    const float* __restrict__ sW, const float* __restrict__ sb,
    float* __restrict__ scores, int R0)
{
    const int tid  = threadIdx.x;
    const int lane = tid & 63;
    const int wn   = tid >> 6;
    const int quad = lane >> 4;
    const int col  = lane & 15;
    const short* wbase = wstream + wn * 2048 + lane * 8;

    float4v acc[2][2];
#pragma unroll
    for (int mi = 0; mi < 2; ++mi)
#pragma unroll
        for (int nt = 0; nt < 2; ++nt) acc[mi][nt] = (float4v){0.f, 0.f, 0.f, 0.f};

    short8v bh[3][2], bl[3][2];
#pragma unroll
    for (int p = 0; p < 2; ++p) {
        if (p < NKC) {
            const short* q = wbase + p * 16384;
            bh[p][0] = *(const short8v*)(q);
            bh[p][1] = *(const short8v*)(q + 512);
            bl[p][0] = *(const short8v*)(q + 1024);
            bl[p][1] = *(const short8v*)(q + 1536);
        }
    }

#pragma unroll
    for (int kc = 0; kc < NKC; ++kc) {
        const int cur = kc % 3;
        if (kc + 2 < NKC) {
            const int nxt = (kc + 2) % 3;
            const short* q = wbase + (kc + 2) * 16384;
            bh[nxt][0] = *(const short8v*)(q);
            bh[nxt][1] = *(const short8v*)(q + 512);
            bl[nxt][0] = *(const short8v*)(q + 1024);
            bl[nxt][1] = *(const short8v*)(q + 1536);
        }
        short8v ah[2], al[2];
#pragma unroll
        for (int mi = 0; mi < 2; ++mi)
            ah[mi] = *(const short8v*)(xAh + ((kc * 2 + mi) * 64 + lane) * 8);
        const bool hlo = (kc >= LO0);
        if (hlo) {
#pragma unroll
            for (int mi = 0; mi < 2; ++mi)
                al[mi] = *(const short8v*)(xAl + (((kc - LO0) * 2 + mi) * 64 + lane) * 8);
        }
#pragma unroll
        for (int mi = 0; mi < 2; ++mi)
#pragma unroll
            for (int nt = 0; nt < 2; ++nt) {
                acc[mi][nt] = mfma_bf16(ah[mi], bh[cur][nt], acc[mi][nt]);
                acc[mi][nt] = mfma_bf16(ah[mi], bl[cur][nt], acc[mi][nt]);
                if (hlo)
                    acc[mi][nt] = mfma_bf16(al[mi], bh[cur][nt], acc[mi][nt]);
            }
    }

    // bias + activation
    float bc0 = bias[wn * 32 + col];
    float bc1 = bias[wn * 32 + 16 + col];
#pragma unroll
    for (int mi = 0; mi < 2; ++mi)
#pragma unroll
        for (int r = 0; r < 4; ++r) {
            float z0 = acc[mi][0][r] + bc0;
            float z1 = acc[mi][1][r] + bc1;
            if (ACT == 0) { z0 = fmaxf(z0, 0.f); z1 = fmaxf(z1, 0.f); }
            else { z0 = (z0 > 0.f) ? z0 : 0.01f * z0; z1 = (z1 > 0.f) ? z1 : 0.01f * z1; }
            acc[mi][0][r] = z0; acc[mi][1][r] = z1;
        }

    __syncthreads();   // all xA reads of this layer done

    if (NORM) {
        float rsum[2][4];
#pragma unroll
        for (int mi = 0; mi < 2; ++mi)
#pragma unroll
            for (int r = 0; r < 4; ++r)
                rsum[mi][r] = quad16_sum(acc[mi][0][r] + acc[mi][1][r]);
        if (col == 0) {
#pragma unroll
            for (int mi = 0; mi < 2; ++mi)
#pragma unroll
                for (int r = 0; r < 4; ++r)
                    ps[wn][mi * 16 + quad * 4 + r] = rsum[mi][r];
        }
        __syncthreads();
        float mu[2][4];
#pragma unroll
        for (int mi = 0; mi < 2; ++mi)
#pragma unroll
            for (int r = 0; r < 4; ++r) {
                int m = mi * 16 + quad * 4 + r;
                float s = 0.f;
#pragma unroll
                for (int w = 0; w < 8; ++w) s += ps[w][m];
                mu[mi][r] = s * (1.f / 256.f);
            }
        __syncthreads();
        float qs[2][4];
#pragma unroll
        for (int mi = 0; mi < 2; ++mi)
#pragma unroll
            for (int r = 0; r < 4; ++r) {
                acc[mi][0][r] -= mu[mi][r];
                acc[mi][1][r] -= mu[mi][r];
                float q = acc[mi][0][r] * acc[mi][0][r]
                        + acc[mi][1][r] * acc[mi][1][r];
                qs[mi][r] = quad16_sum(q);
            }
        if (col == 0) {
#pragma unroll
            for (int mi = 0; mi < 2; ++mi)
#pragma unroll
                for (int r = 0; r < 4; ++r)
                    ps[wn][mi * 16 + quad * 4 + r] = qs[mi][r];
        }
        __syncthreads();
#pragma unroll
        for (int mi = 0; mi < 2; ++mi)
#pragma unroll
            for (int r = 0; r < 4; ++r) {
                int m = mi * 16 + quad * 4 + r;
                float s = 0.f;
#pragma unroll
                for (int w = 0; w < 8; ++w) s += ps[w][m];
                float rsf = 1.0f / sqrtf(s * (1.f / 256.f) + 1e-5f);
                acc[mi][0][r] *= rsf;
                acc[mi][1][r] *= rsf;
            }
    }

    if (SCORE) {
        __syncthreads();
        float sv0 = sW[wn * 32 + col];
        float sv1 = sW[wn * 32 + 16 + col];
        float psu[2][4];
#pragma unroll
        for (int mi = 0; mi < 2; ++mi)
#pragma unroll
            for (int r = 0; r < 4; ++r)
                psu[mi][r] = quad16_sum(acc[mi][0][r] * sv0 + acc[mi][1][r] * sv1);
        if (col == 0) {
#pragma unroll
            for (int mi = 0; mi < 2; ++mi)
#pragma unroll
                for (int r = 0; r < 4; ++r)
                    ps[wn][mi * 16 + quad * 4 + r] = psu[mi][r];
        }
        __syncthreads();
        if (tid < 32) {
            float s = sb[0];
#pragma unroll
            for (int w = 0; w < 8; ++w) s += ps[w][tid];
            scores[R0 + tid] = s;
        }
    } else {
        // writeback to next layer's A-frag layout; wave wn owns kc2 = wn.
#pragma unroll
        for (int mi = 0; mi < 2; ++mi)
#pragma unroll
            for (int nt = 0; nt < 2; ++nt) {
                int nn0 = (nt * 16 + col) & ~1;    // k within 32-chunk
                int q2  = nn0 >> 3;
                int j0  = nn0 & 7;
#pragma unroll
                for (int r = 0; r < 4; ++r) {
                    float v  = acc[mi][nt][r];
                    float pv = __shfl_xor(v, 1, 64);
                    int m15 = quad * 4 + r;
                    int rowidx = (wn * 2 + mi) * 64 + q2 * 16 + m15;
                    if ((col & 1) == 0) {
                        unsigned int wd = (unsigned int)bf16_rn(v)
                                        | ((unsigned int)bf16_rn(pv) << 16);
                        ((unsigned int*)xAh)[rowidx * 4 + (j0 >> 1)] = wd;
                    } else {
                        float ls = v  - bf16_val(bf16_rn(v));
                        float lp = pv - bf16_val(bf16_rn(pv));
                        unsigned int wd = (unsigned int)bf16_rn(lp)
                                        | ((unsigned int)bf16_rn(ls) << 16);
                        ((unsigned int*)xAl)[rowidx * 4 + (j0 >> 1)] = wd;
                    }
                }
            }
        __syncthreads();
    }
}

__global__ __launch_bounds__(512, 4) void k_mlp(
    const float* __restrict__ x0, const short* __restrict__ wprep,
    const float* __restrict__ cb,  const float* __restrict__ l1b,
    const float* __restrict__ l2ab, const float* __restrict__ l2bb,
    const float* __restrict__ sW,  const float* __restrict__ sb,
    float* __restrict__ scores)
{
    __shared__ __align__(16) char smem[76288];
    short*  xAh = (short*)smem;
    float*  xf  = (float*)(smem + OFF_XF);
    short*  xAl = (short*)(smem + OFF_XAL);
    float (*ps)[32] = (float(*)[32])(smem + OFF_PS);

    const int tid = threadIdx.x;
    const int fb  = blockIdx.x;          // 0..1023, 32 rows each
    const int R0  = fb * 32;

    // phase A: coalesced load of 32 x0 rows (32*268 = 8576 f32 = 2144 float4)
    {
        const float4* src = (const float4*)(x0 + (size_t)fb * 32 * XF_STRIDE);
        for (int i = tid; i < 2144; i += 512) ((float4*)xf)[i] = src[i];
    }
    __syncthreads();

    // phase B: build A-frags (therm from counts + f32 -> hi/lo)
    {
#pragma unroll
        for (int g0 = 0; g0 < 3; ++g0) {
            int g  = tid + g0 * 512;     // 0..1535 : [kc 12][mi 2][lane 64]
            int lt = g & 63;
            int t2 = g >> 6;
            int kc = t2 >> 1, mi = t2 & 1;
            int m  = mi * 16 + (lt & 15);
            int kb = (lt >> 4) * 8;
            if (kc < 4) {
                float c[5];
#pragma unroll
                for (int e = 0; e < 5; ++e) c[e] = xf[m * XF_STRIDE + 256 + e];
                short8v hv;
#pragma unroll
                for (int j = 0; j < 8; ++j) {
                    int kp = kc * 32 + kb + j;
                    float val = 0.f;
                    if (kp < 100) {
                        int e = kp / 20;
                        val = ((float)(kp - e * 20) < c[e]) ? 1.0f : 0.0f;
                    }
                    hv[j] = (short)bf16_rn(val);
                }
                *(short8v*)(xAh + g * 8) = hv;
            } else {
                const float* srcp = xf + m * XF_STRIDE + (kc - 4) * 32 + kb;
                float4 f0 = *(const float4*)(srcp);
                float4 f1 = *(const float4*)(srcp + 4);
                float fv[8] = {f0.x, f0.y, f0.z, f0.w, f1.x, f1.y, f1.z, f1.w};
                short8v hv, lv;
#pragma unroll
                for (int j = 0; j < 8; ++j) {
                    unsigned short h = bf16_rn(fv[j]);
                    hv[j] = (short)h;
                    lv[j] = (short)bf16_rn(fv[j] - bf16_val(h));
                }
                *(short8v*)(xAh + g * 8) = hv;
                *(short8v*)(xAl + (g - 512) * 8) = lv;
            }
        }
    }
    __syncthreads();

    layer_pass<12, 4, 0, true,  false>(xAh, xAl, ps, wprep,
        cb, nullptr, nullptr, nullptr, R0);
    layer_pass< 8, 0, 0, false, false>(xAh, xAl, ps, wprep + 12 * 16384,
        l1b, nullptr, nullptr, nullptr, R0);
    layer_pass< 8, 0, 1, false, false>(xAh, xAl, ps, wprep + 20 * 16384,
        l2ab, nullptr, nullptr, nullptr, R0);
    layer_pass< 8, 0, 0, true,  true >(xAh, xAl, ps, wprep + 28 * 16384,
        l2bb, sW, sb, scores, R0);
}

// ---------------- softmax / zero / scatter ----------------
__global__ __launch_bounds__(256) void k_softmax(float* __restrict__ probs) {
    const int b   = blockIdx.x;
    const int tid = threadIdx.x;
    __shared__ float redA[4];
    __shared__ float redB[4];
    float* sp = probs + (size_t)b * S_DIM;

    float v[16];
    float mx = -INFINITY;
#pragma unroll
    for (int i = 0; i < 16; ++i) {
        v[i] = sp[tid + i * 256];
        mx = fmaxf(mx, v[i]);
    }
    mx = wave_max(mx);
    if ((tid & 63) == 0) redA[tid >> 6] = mx;
    __syncthreads();
    mx = fmaxf(fmaxf(redA[0], redA[1]), fmaxf(redA[2], redA[3]));

    float sum = 0.f;
#pragma unroll
    for (int i = 0; i < 16; ++i) {
        v[i] = expf(v[i] - mx);
        sum += v[i];
    }
    sum = wave_sum(sum);
    if ((tid & 63) == 0) redB[tid >> 6] = sum;
    __syncthreads();
    float tot = redB[0] + redB[1] + redB[2] + redB[3];
    float inv = 1.0f / tot;
#pragma unroll
    for (int i = 0; i < 16; ++i) sp[tid + i * 256] = v[i] * inv;
}

__global__ __launch_bounds__(256) void k_zero4(float4* __restrict__ p, int n4) {
    int i = blockIdx.x * 256 + threadIdx.x;
    if (i < n4) p[i] = make_float4(0.f, 0.f, 0.f, 0.f);
}

__global__ __launch_bounds__(256) void k_scatter(
    const int*   __restrict__ mass_idx,
    const float* __restrict__ intensity,
    const float* __restrict__ probs,
    float* __restrict__ spect)
{
    int i  = blockIdx.x * 256 + threadIdx.x;
    int bs = i >> 5;
    int b  = i >> 17;
    float w = intensity[i] * probs[bs];
    unsafeAtomicAdd(spect + ((size_t)b << 16) + mass_idx[i], w);
}

// ---------------- launch ----------------
extern "C" void kernel_launch(void* const* d_in, const int* in_sizes, int n_in,
                              void* d_out, int out_size, void* d_ws, size_t ws_size,
                              hipStream_t stream) {
    const float* vert_feat = (const float*)d_in[0];
    const float* vert_mask = (const float*)d_in[1];
    const float* elem_oh   = (const float*)d_in[2];
    const int*   subsets   = (const int*)d_in[4];
    const int*   mass_idx  = (const int*)d_in[6];
    const float* intensity = (const float*)d_in[7];
    const float* combine_W = (const float*)d_in[8];
    const float* combine_b = (const float*)d_in[9];
    const float* l1_W      = (const float*)d_in[10];
    const float* l1_b      = (const float*)d_in[11];
    const float* l2a_W     = (const float*)d_in[12];
    const float* l2a_b     = (const float*)d_in[13];
    const float* l2b_W     = (const float*)d_in[14];
    const float* l2b_b     = (const float*)d_in[15];
    const float* score_W   = (const float*)d_in[16];
    const float* score_b   = (const float*)d_in[17];

    float* out   = (float*)d_out;
    float* spect = out;                           // B*NBINS
    float* probs = out + (size_t)B_DIM * NBINS;   // B*S (scores -> probs in place)

    short* wprep = (short*)d_ws;                          // 1.125 MB
    float* x0    = (float*)(wprep + 36 * 16384);          // 32768*268 f32 ≈ 35.1 MB

    k_wprep<<<1152, 256, 0, stream>>>(combine_W, l1_W, l2a_W, l2b_W, wprep);
    k_features<<<4096, 256, 0, stream>>>(vert_feat, vert_mask, elem_oh, subsets, x0);
    k_mlp<<<1024, 512, 0, stream>>>(x0, wprep,
        combine_b, l1_b, l2a_b, l2b_b, score_W, score_b, probs);
    k_softmax<<<B_DIM, 256, 0, stream>>>(probs);
    k_zero4<<<(B_DIM * NBINS / 4) / 256, 256, 0, stream>>>(
        (float4*)spect, B_DIM * NBINS / 4);
    k_scatter<<<(B_DIM * S_DIM * P_DIM) / 256, 256, 0, stream>>>(
        mass_idx, intensity, probs, spect);
}

// Round 7
// 266.210 us; speedup vs baseline: 1.9450x; 1.0692x over previous
//
#include <hip/hip_runtime.h>
#include <math.h>

// Problem constants
#define B_DIM 8
#define A_DIM 48
#define GF_DIM 256
#define S_DIM 4096
#define P_DIM 32
#define E_DIM 5
#define OHN 100
#define NBINS 65536

typedef __attribute__((ext_vector_type(8))) short short8v;
typedef __attribute__((ext_vector_type(4))) float float4v;

// ---------------- helpers ----------------
__device__ __forceinline__ float wave_sum(float v) {
#pragma unroll
    for (int o = 32; o; o >>= 1) v += __shfl_xor(v, o, 64);
    return v;
}
__device__ __forceinline__ float wave_max(float v) {
#pragma unroll
    for (int o = 32; o; o >>= 1) v = fmaxf(v, __shfl_xor(v, o, 64));
    return v;
}
__device__ __forceinline__ float quad16_sum(float v) {
    v += __shfl_xor(v, 1, 64); v += __shfl_xor(v, 2, 64);
    v += __shfl_xor(v, 4, 64); v += __shfl_xor(v, 8, 64);
    return v;
}
__device__ __forceinline__ unsigned short bf16_rn(float x) {
    unsigned int u = __float_as_uint(x);
    return (unsigned short)((u + 0x7FFFu + ((u >> 16) & 1u)) >> 16);
}
__device__ __forceinline__ float bf16_val(unsigned short h) {
    return __uint_as_float(((unsigned int)h) << 16);
}
__device__ __forceinline__ float4v mfma_bf16(short8v a, short8v b, float4v c) {
    return __builtin_amdgcn_mfma_f32_16x16x32_bf16(a, b, c, 0, 0, 0);
}

// ---------------- prep: W hi/lo streams + vert*mask^2 streams + mask/ei ------
// Blocks 0..1151: MLP W streams (36 chunks x 16384 shorts). Chunk c,
// frag_id = wn*4 + hl*2 + nt; frag 512 shorts: (lane,j) =
// W[k = c_rel*32 + (lane>>4)*8 + j][n = wn*32 + nt*16 + (lane&15)].
// Chunks 0..11 combine (therm k' 0..99, pad 100..127, normed -> 128..383);
// 12..19 l1; 20..27 l2a; 28..35 l2b.
// Blocks 1152..1663: vertB (16 chunks: batch b = vc>>1, v = vc&1; K = v*32+...,
// val = vert_feat[b][k][n] * mask[b][k]^2, zero-padded k>=48).
// Block 1664: maskB (8x48 f32), eiB (8x48 int) — grid-stride, 384 > 256!
__global__ __launch_bounds__(256) void k_prep(
    const float* __restrict__ cW, const float* __restrict__ l1W,
    const float* __restrict__ l2aW, const float* __restrict__ l2bW,
    const float* __restrict__ vert_feat, const float* __restrict__ vert_mask,
    const float* __restrict__ elem_oh,
    short* __restrict__ wp, short* __restrict__ wv,
    float* __restrict__ maskB, int* __restrict__ eiB)
{
    const int blk = blockIdx.x;
    const int tid = threadIdx.x;
    if (blk < 1152) {
        int e = blk * 256 + tid;              // < 36*8192
        int c = e >> 13;
        int i = e & 8191;
        int j    = i & 7;
        int lane = (i >> 3) & 63;
        int nt   = (i >> 9) & 1;
        int wn   = i >> 10;
        int krel = (lane >> 4) * 8 + j;
        int n    = wn * 32 + nt * 16 + (lane & 15);
        float val = 0.f;
        if (c < 12) {
            int kp = c * 32 + krel;
            if (kp < 100)       val = cW[kp * 256 + n];
            else if (kp >= 128) val = cW[(kp - 28) * 256 + n];
        } else {
            int L  = (c - 12) >> 3;
            int kc = (c - 12) & 7;
            const float* W = (L == 0) ? l1W : (L == 1) ? l2aW : l2bW;
            val = W[(kc * 32 + krel) * 256 + n];
        }
        unsigned short h = bf16_rn(val);
        float lo = val - bf16_val(h);
        int base = c * 16384 + (i & 511);
        wp[base + (wn * 4 + nt) * 512]     = (short)h;
        wp[base + (wn * 4 + 2 + nt) * 512] = (short)bf16_rn(lo);
    } else if (blk < 1664) {
        int vb = blk - 1152;
        int vc = vb >> 5;                     // 0..15
        int i  = (vb & 31) * 256 + tid;       // 0..8191
        int b  = vc >> 1, v = vc & 1;
        int j    = i & 7;
        int lane = (i >> 3) & 63;
        int nt   = (i >> 9) & 1;
        int wn   = i >> 10;
        int k = v * 32 + (lane >> 4) * 8 + j;
        int n = wn * 32 + nt * 16 + (lane & 15);
        float val = 0.f;
        if (k < A_DIM) {
            float mk = vert_mask[b * A_DIM + k];
            val = vert_feat[((size_t)(b * A_DIM + k)) * GF_DIM + n] * mk * mk;
        }
        unsigned short h = bf16_rn(val);
        float lo = val - bf16_val(h);
        int base = vc * 16384 + (i & 511);
        wv[base + (wn * 4 + nt) * 512]     = (short)h;
        wv[base + (wn * 4 + 2 + nt) * 512] = (short)bf16_rn(lo);
    } else {
        // FIX (R6 bug): 384 entries with 256 threads -> grid-stride loop.
        for (int t = tid; t < B_DIM * A_DIM; t += 256) {
            maskB[t] = vert_mask[t];
            int ei = 0;
#pragma unroll
            for (int e = 0; e < E_DIM; ++e)
                if (elem_oh[t * E_DIM + e] > 0.5f) ei = e;
            eiB[t] = ei;
        }
    }
}

// ---------------- MLP kernel: M=32/block, 3 blocks/CU ----------------
// LDS: xAh 24576 | xAl 16384 | fm 4096 | ps 1024 | cnt 640 | invsz 128
#define L_XAL 24576
#define L_FM  40960
#define L_PS  45056
#define L_CNT 46080
#define L_INV 46720
#define L_TOT 46848

// One GEMM layer, barrier-free K loop; W slice in regs (depth-2 prefetch).
template <int NKC, int LO0, int ACT, bool NORM, bool SCORE>
__device__ __forceinline__ void layer_pass(
    short* xAh, short* xAl, float (*ps)[32],
    const short* __restrict__ wstream, const float* __restrict__ bias,
    const float* __restrict__ sW, const float* __restrict__ sb,
    float* __restrict__ scores, int R0)
{
    const int tid  = threadIdx.x;
    const int lane = tid & 63;
    const int wn   = tid >> 6;
    const int quad = lane >> 4;
    const int col  = lane & 15;
    const short* wbase = wstream + wn * 2048 + lane * 8;

    float4v acc[2][2];
#pragma unroll
    for (int mi = 0; mi < 2; ++mi)
#pragma unroll
        for (int nt = 0; nt < 2; ++nt) acc[mi][nt] = (float4v){0.f, 0.f, 0.f, 0.f};

    short8v bh[3][2], bl[3][2];
#pragma unroll
    for (int p = 0; p < 2; ++p) {
        if (p < NKC) {
            const short* q = wbase + p * 16384;
            bh[p][0] = *(const short8v*)(q);
            bh[p][1] = *(const short8v*)(q + 512);
            bl[p][0] = *(const short8v*)(q + 1024);
            bl[p][1] = *(const short8v*)(q + 1536);
        }
    }

#pragma unroll
    for (int kc = 0; kc < NKC; ++kc) {
        const int cur = kc % 3;
        if (kc + 2 < NKC) {
            const int nxt = (kc + 2) % 3;
            const short* q = wbase + (kc + 2) * 16384;
            bh[nxt][0] = *(const short8v*)(q);
            bh[nxt][1] = *(const short8v*)(q + 512);
            bl[nxt][0] = *(const short8v*)(q + 1024);
            bl[nxt][1] = *(const short8v*)(q + 1536);
        }
        short8v ah[2], al[2];
#pragma unroll
        for (int mi = 0; mi < 2; ++mi)
            ah[mi] = *(const short8v*)(xAh + ((kc * 2 + mi) * 64 + lane) * 8);
        const bool hlo = (kc >= LO0);
        if (hlo) {
#pragma unroll
            for (int mi = 0; mi < 2; ++mi)
                al[mi] = *(const short8v*)(xAl + (((kc - LO0) * 2 + mi) * 64 + lane) * 8);
        }
#pragma unroll
        for (int mi = 0; mi < 2; ++mi)
#pragma unroll
            for (int nt = 0; nt < 2; ++nt) {
                acc[mi][nt] = mfma_bf16(ah[mi], bh[cur][nt], acc[mi][nt]);
                acc[mi][nt] = mfma_bf16(ah[mi], bl[cur][nt], acc[mi][nt]);
                if (hlo)
                    acc[mi][nt] = mfma_bf16(al[mi], bh[cur][nt], acc[mi][nt]);
            }
    }

    // bias + activation
    float bc0 = bias[wn * 32 + col];
    float bc1 = bias[wn * 32 + 16 + col];
#pragma unroll
    for (int mi = 0; mi < 2; ++mi)
#pragma unroll
        for (int r = 0; r < 4; ++r) {
            float z0 = acc[mi][0][r] + bc0;
            float z1 = acc[mi][1][r] + bc1;
            if (ACT == 0) { z0 = fmaxf(z0, 0.f); z1 = fmaxf(z1, 0.f); }
            else { z0 = (z0 > 0.f) ? z0 : 0.01f * z0; z1 = (z1 > 0.f) ? z1 : 0.01f * z1; }
            acc[mi][0][r] = z0; acc[mi][1][r] = z1;
        }

    __syncthreads();   // all xA reads of this layer done

    if (NORM) {
        float rsum[2][4];
#pragma unroll
        for (int mi = 0; mi < 2; ++mi)
#pragma unroll
            for (int r = 0; r < 4; ++r)
                rsum[mi][r] = quad16_sum(acc[mi][0][r] + acc[mi][1][r]);
        if (col == 0) {
#pragma unroll
            for (int mi = 0; mi < 2; ++mi)
#pragma unroll
                for (int r = 0; r < 4; ++r)
                    ps[wn][mi * 16 + quad * 4 + r] = rsum[mi][r];
        }
        __syncthreads();
        float mu[2][4];
#pragma unroll
        for (int mi = 0; mi < 2; ++mi)
#pragma unroll
            for (int r = 0; r < 4; ++r) {
                int m = mi * 16 + quad * 4 + r;
                float s = 0.f;
#pragma unroll
                for (int w = 0; w < 8; ++w) s += ps[w][m];
                mu[mi][r] = s * (1.f / 256.f);
            }
        __syncthreads();
        float qs[2][4];
#pragma unroll
        for (int mi = 0; mi < 2; ++mi)
#pragma unroll
            for (int r = 0; r < 4; ++r) {
                acc[mi][0][r] -= mu[mi][r];
                acc[mi][1][r] -= mu[mi][r];
                float q = acc[mi][0][r] * acc[mi][0][r]
                        + acc[mi][1][r] * acc[mi][1][r];
                qs[mi][r] = quad16_sum(q);
            }
        if (col == 0) {
#pragma unroll
            for (int mi = 0; mi < 2; ++mi)
#pragma unroll
                for (int r = 0; r < 4; ++r)
                    ps[wn][mi * 16 + quad * 4 + r] = qs[mi][r];
        }
        __syncthreads();
#pragma unroll
        for (int mi = 0; mi < 2; ++mi)
#pragma unroll
            for (int r = 0; r < 4; ++r) {
                int m = mi * 16 + quad * 4 + r;
                float s = 0.f;
#pragma unroll
                for (int w = 0; w < 8; ++w) s += ps[w][m];
                float rsf = 1.0f / sqrtf(s * (1.f / 256.f) + 1e-5f);
                acc[mi][0][r] *= rsf;
                acc[mi][1][r] *= rsf;
            }
    }

    if (SCORE) {
        __syncthreads();
        float sv0 = sW[wn * 32 + col];
        float sv1 = sW[wn * 32 + 16 + col];
        float psu[2][4];
#pragma unroll
        for (int mi = 0; mi < 2; ++mi)
#pragma unroll
            for (int r = 0; r < 4; ++r)
                psu[mi][r] = quad16_sum(acc[mi][0][r] * sv0 + acc[mi][1][r] * sv1);
        if (col == 0) {
#pragma unroll
            for (int mi = 0; mi < 2; ++mi)
#pragma unroll
                for (int r = 0; r < 4; ++r)
                    ps[wn][mi * 16 + quad * 4 + r] = psu[mi][r];
        }
        __syncthreads();
        if (tid < 32) {
            float s = sb[0];
#pragma unroll
            for (int w = 0; w < 8; ++w) s += ps[w][tid];
            scores[R0 + tid] = s;
        }
    } else {
        // writeback to next layer's A-frag layout; wave wn owns k-chunk wn.
#pragma unroll
        for (int mi = 0; mi < 2; ++mi)
#pragma unroll
            for (int nt = 0; nt < 2; ++nt) {
                int nn0 = (nt * 16 + col) & ~1;
                int q2  = nn0 >> 3;
                int j0  = nn0 & 7;
#pragma unroll
                for (int r = 0; r < 4; ++r) {
                    float v  = acc[mi][nt][r];
                    float pv = __shfl_xor(v, 1, 64);
                    int m15 = quad * 4 + r;
                    int rowidx = (wn * 2 + mi) * 64 + q2 * 16 + m15;
                    if ((col & 1) == 0) {
                        unsigned int wd = (unsigned int)bf16_rn(v)
                                        | ((unsigned int)bf16_rn(pv) << 16);
                        ((unsigned int*)xAh)[rowidx * 4 + (j0 >> 1)] = wd;
                    } else {
                        float ls = v  - bf16_val(bf16_rn(v));
                        float lp = pv - bf16_val(bf16_rn(pv));
                        unsigned int wd = (unsigned int)bf16_rn(lp)
                                        | ((unsigned int)bf16_rn(ls) << 16);
                        ((unsigned int*)xAl)[rowidx * 4 + (j0 >> 1)] = wd;
                    }
                }
            }
        __syncthreads();
    }
}

__global__ __launch_bounds__(512, 6) void k_mlp(
    const int* __restrict__ subsets, const short* __restrict__ wprep,
    const short* __restrict__ vertB,
    const float* __restrict__ maskB, const int* __restrict__ eiB,
    const float* __restrict__ cb,  const float* __restrict__ l1b,
    const float* __restrict__ l2ab, const float* __restrict__ l2bb,
    const float* __restrict__ sW,  const float* __restrict__ sb,
    float* __restrict__ scores)
{
    __shared__ __align__(16) char smem[L_TOT];
    short*  xAh = (short*)smem;
    short*  xAl = (short*)(smem + L_XAL);
    short*  fm  = (short*)(smem + L_FM);
    float (*ps)[32]  = (float(*)[32])(smem + L_PS);
    float (*cnt)[5]  = (float(*)[5])(smem + L_CNT);
    float*  invsz    = (float*)(smem + L_INV);

    const int tid  = threadIdx.x;
    const int lane = tid & 63;
    const int wn   = tid >> 6;
    const int quad = lane >> 4;
    const int col  = lane & 15;
    const int fb   = blockIdx.x;          // 0..1023, 32 rows each
    const int b    = fb >> 7;
    const int R0   = fb * 32;

    // ---- phase A1: subset flags -> exact-bf16 A-frags (K=64, k>=48 zero) ----
    if (tid < 256) {
        int g  = tid;
        int lg = g & 63;
        int t2 = g >> 6;                  // kc*2 + mi
        int kc = t2 >> 1, mi = t2 & 1;
        int m  = mi * 16 + (lg & 15);
        int k0 = kc * 32 + (lg >> 4) * 8;
        const int* srow = subsets + (size_t)(R0 + m) * A_DIM;
        short8v hv;
#pragma unroll
        for (int j = 0; j < 8; ++j) {
            int k = k0 + j;
            hv[j] = (short)((k < A_DIM && srow[k]) ? 0x3F80 : 0);
        }
        *(short8v*)(fm + g * 8) = hv;
    }

    // ---- phase A2: per-row element counts (ballot) + 1/subset_size ----
    {
        const float mymask = (lane < A_DIM) ? maskB[b * A_DIM + lane] : 0.f;
        const int   myei   = (lane < A_DIM) ? eiB[b * A_DIM + lane]   : -1;
#pragma unroll
        for (int i = 0; i < 4; ++i) {
            int r = wn * 4 + i;
            int fl = (lane < A_DIM) ? subsets[(size_t)(R0 + r) * A_DIM + lane] : 0;
            unsigned long long m0 = __ballot(fl != 0 && myei == 0);
            unsigned long long m1 = __ballot(fl != 0 && myei == 1);
            unsigned long long m2 = __ballot(fl != 0 && myei == 2);
            unsigned long long m3 = __ballot(fl != 0 && myei == 3);
            unsigned long long m4 = __ballot(fl != 0 && myei == 4);
            float ssz = wave_sum(fl ? mymask : 0.f) + 1e-4f;
            if (lane == 0) {
                cnt[r][0] = (float)__popcll(m0);
                cnt[r][1] = (float)__popcll(m1);
                cnt[r][2] = (float)__popcll(m2);
                cnt[r][3] = (float)__popcll(m3);
                cnt[r][4] = (float)__popcll(m4);
                invsz[r]  = 1.0f / ssz;
            }
        }
    }
    __syncthreads();

    // ---- layer 0: sws = flags @ (vert*mask^2), /size, inorm -> combine input
    {
        const short* wbase = vertB + b * 32768 + wn * 2048 + lane * 8;
        float4v acc[2][2];
#pragma unroll
        for (int mi = 0; mi < 2; ++mi)
#pragma unroll
            for (int nt = 0; nt < 2; ++nt) acc[mi][nt] = (float4v){0.f, 0.f, 0.f, 0.f};

        short8v bh[2][2], bl[2][2];
#pragma unroll
        for (int kc = 0; kc < 2; ++kc) {
            const short* q = wbase + kc * 16384;
            bh[kc][0] = *(const short8v*)(q);
            bh[kc][1] = *(const short8v*)(q + 512);
            bl[kc][0] = *(const short8v*)(q + 1024);
            bl[kc][1] = *(const short8v*)(q + 1536);
        }
#pragma unroll
        for (int kc = 0; kc < 2; ++kc) {
            short8v a0 = *(const short8v*)(fm + ((kc * 2 + 0) * 64 + lane) * 8);
            short8v a1 = *(const short8v*)(fm + ((kc * 2 + 1) * 64 + lane) * 8);
#pragma unroll
            for (int nt = 0; nt < 2; ++nt) {
                acc[0][nt] = mfma_bf16(a0, bh[kc][nt], acc[0][nt]);
                acc[0][nt] = mfma_bf16(a0, bl[kc][nt], acc[0][nt]);
                acc[1][nt] = mfma_bf16(a1, bh[kc][nt], acc[1][nt]);
                acc[1][nt] = mfma_bf16(a1, bl[kc][nt], acc[1][nt]);
            }
        }

        // mean = sws / subset_size
#pragma unroll
        for (int mi = 0; mi < 2; ++mi)
#pragma unroll
            for (int r = 0; r < 4; ++r) {
                float iv = invsz[mi * 16 + quad * 4 + r];
                acc[mi][0][r] *= iv;
                acc[mi][1][r] *= iv;
            }

        __syncthreads();

        // instance norm over 256 cols
        {
            float rsum[2][4];
#pragma unroll
            for (int mi = 0; mi < 2; ++mi)
#pragma unroll
                for (int r = 0; r < 4; ++r)
                    rsum[mi][r] = quad16_sum(acc[mi][0][r] + acc[mi][1][r]);
            if (col == 0) {
#pragma unroll
                for (int mi = 0; mi < 2; ++mi)
#pragma unroll
                    for (int r = 0; r < 4; ++r)
                        ps[wn][mi * 16 + quad * 4 + r] = rsum[mi][r];
            }
            __syncthreads();
            float mu[2][4];
#pragma unroll
            for (int mi = 0; mi < 2; ++mi)
#pragma unroll
                for (int r = 0; r < 4; ++r) {
                    int m = mi * 16 + quad * 4 + r;
                    float s = 0.f;
#pragma unroll
                    for (int w = 0; w < 8; ++w) s += ps[w][m];
                    mu[mi][r] = s * (1.f / 256.f);
                }
            __syncthreads();
            float qs[2][4];
#pragma unroll
            for (int mi = 0; mi < 2; ++mi)
#pragma unroll
                for (int r = 0; r < 4; ++r) {
                    acc[mi][0][r] -= mu[mi][r];
                    acc[mi][1][r] -= mu[mi][r];
                    float q = acc[mi][0][r] * acc[mi][0][r]
                            + acc[mi][1][r] * acc[mi][1][r];
                    qs[mi][r] = quad16_sum(q);
                }
            if (col == 0) {
#pragma unroll
                for (int mi = 0; mi < 2; ++mi)
#pragma unroll
                    for (int r = 0; r < 4; ++r)
                        ps[wn][mi * 16 + quad * 4 + r] = qs[mi][r];
            }
            __syncthreads();
#pragma unroll
            for (int mi = 0; mi < 2; ++mi)
#pragma unroll
                for (int r = 0; r < 4; ++r) {
                    int m = mi * 16 + quad * 4 + r;
                    float s = 0.f;
#pragma unroll
                    for (int w = 0; w < 8; ++w) s += ps[w][m];
                    float rsf = 1.0f / sqrtf(s * (1.f / 256.f) + 1e-5f);
                    acc[mi][0][r] *= rsf;
                    acc[mi][1][r] *= rsf;
                }
        }

        // writeback: normed cols n -> combine k' = 128+n (xAh kc 4+wn, xAl chunk wn)
#pragma unroll
        for (int mi = 0; mi < 2; ++mi)
#pragma unroll
            for (int nt = 0; nt < 2; ++nt) {
                int nn0 = (nt * 16 + col) & ~1;
                int q2  = nn0 >> 3;
                int j0  = nn0 & 7;
#pragma unroll
                for (int r = 0; r < 4; ++r) {
                    float v  = acc[mi][nt][r];
                    float pv = __shfl_xor(v, 1, 64);
                    int m15 = quad * 4 + r;
                    int rh = ((4 + wn) * 2 + mi) * 64 + q2 * 16 + m15;
                    int rl = (wn * 2 + mi) * 64 + q2 * 16 + m15;
                    if ((col & 1) == 0) {
                        unsigned int wd = (unsigned int)bf16_rn(v)
                                        | ((unsigned int)bf16_rn(pv) << 16);
                        ((unsigned int*)xAh)[rh * 4 + (j0 >> 1)] = wd;
                    } else {
                        float ls = v  - bf16_val(bf16_rn(v));
                        float lp = pv - bf16_val(bf16_rn(pv));
                        unsigned int wd = (unsigned int)bf16_rn(lp)
                                        | ((unsigned int)bf16_rn(ls) << 16);
                        ((unsigned int*)xAl)[rl * 4 + (j0 >> 1)] = wd;
                    }
                }
            }

        // thermometer frags into xAh kc 0..3 (512 groups == 512 threads)
        {
            int g  = tid;
            int lg = g & 63;
            int t2 = g >> 6;                 // kc*2 + mi, kc 0..3
            int kc = t2 >> 1, mi = t2 & 1;
            int m  = mi * 16 + (lg & 15);
            int kb = (lg >> 4) * 8;
            float c0 = cnt[m][0], c1 = cnt[m][1], c2 = cnt[m][2],
                  c3 = cnt[m][3], c4 = cnt[m][4];
            short8v hv;
#pragma unroll
            for (int j = 0; j < 8; ++j) {
                int kp = kc * 32 + kb + j;
                float val = 0.f;
                if (kp < 100) {
                    int e = kp / 20;
                    float ce = (e == 0) ? c0 : (e == 1) ? c1 : (e == 2) ? c2
                             : (e == 3) ? c3 : c4;
                    val = ((float)(kp - e * 20) < ce) ? 1.0f : 0.0f;
                }
                hv[j] = (short)((val != 0.f) ? 0x3F80 : 0);
            }
            *(short8v*)(xAh + g * 8) = hv;
        }
        __syncthreads();
    }

    // ---- layers 1..4 ----
    layer_pass<12, 4, 0, true,  false>(xAh, xAl, ps, wprep,
        cb, nullptr, nullptr, nullptr, R0);
    layer_pass< 8, 0, 0, false, false>(xAh, xAl, ps, wprep + 12 * 16384,
        l1b, nullptr, nullptr, nullptr, R0);
    layer_pass< 8, 0, 1, false, false>(xAh, xAl, ps, wprep + 20 * 16384,
        l2ab, nullptr, nullptr, nullptr, R0);
    layer_pass< 8, 0, 0, true,  true >(xAh, xAl, ps, wprep + 28 * 16384,
        l2bb, sW, sb, scores, R0);
}

// ---------------- softmax / zero / scatter ----------------
__global__ __launch_bounds__(256) void k_softmax(float* __restrict__ probs) {
    const int b   = blockIdx.x;
    const int tid = threadIdx.x;
    __shared__ float redA[4];
    __shared__ float redB[4];
    float* sp = probs + (size_t)b * S_DIM;

    float v[16];
    float mx = -INFINITY;
#pragma unroll
    for (int i = 0; i < 16; ++i) {
        v[i] = sp[tid + i * 256];
        mx = fmaxf(mx, v[i]);
    }
    mx = wave_max(mx);
    if ((tid & 63) == 0) redA[tid >> 6] = mx;
    __syncthreads();
    mx = fmaxf(fmaxf(redA[0], redA[1]), fmaxf(redA[2], redA[3]));

    float sum = 0.f;
#pragma unroll
    for (int i = 0; i < 16; ++i) {
        v[i] = expf(v[i] - mx);
        sum += v[i];
    }
    sum = wave_sum(sum);
    if ((tid & 63) == 0) redB[tid >> 6] = sum;
    __syncthreads();
    float tot = redB[0] + redB[1] + redB[2] + redB[3];
    float inv = 1.0f / tot;
#pragma unroll
    for (int i = 0; i < 16; ++i) sp[tid + i * 256] = v[i] * inv;
}

__global__ __launch_bounds__(256) void k_zero4(float4* __restrict__ p, int n4) {
    int i = blockIdx.x * 256 + threadIdx.x;
    if (i < n4) p[i] = make_float4(0.f, 0.f, 0.f, 0.f);
}

__global__ __launch_bounds__(256) void k_scatter(
    const int*   __restrict__ mass_idx,
    const float* __restrict__ intensity,
    const float* __restrict__ probs,
    float* __restrict__ spect)
{
    int i  = blockIdx.x * 256 + threadIdx.x;
    int bs = i >> 5;
    int b  = i >> 17;
    float w = intensity[i] * probs[bs];
    unsafeAtomicAdd(spect + ((size_t)b << 16) + mass_idx[i], w);
}

// ---------------- launch ----------------
extern "C" void kernel_launch(void* const* d_in, const int* in_sizes, int n_in,
                              void* d_out, int out_size, void* d_ws, size_t ws_size,
                              hipStream_t stream) {
    const float* vert_feat = (const float*)d_in[0];
    const float* vert_mask = (const float*)d_in[1];
    const float* elem_oh   = (const float*)d_in[2];
    const int*   subsets   = (const int*)d_in[4];
    const int*   mass_idx  = (const int*)d_in[6];
    const float* intensity = (const float*)d_in[7];
    const float* combine_W = (const float*)d_in[8];
    const float* combine_b = (const float*)d_in[9];
    const float* l1_W      = (const float*)d_in[10];
    const float* l1_b      = (const float*)d_in[11];
    const float* l2a_W     = (const float*)d_in[12];
    const float* l2a_b     = (const float*)d_in[13];
    const float* l2b_W     = (const float*)d_in[14];
    const float* l2b_b     = (const float*)d_in[15];
    const float* score_W   = (const float*)d_in[16];
    const float* score_b   = (const float*)d_in[17];

    float* out   = (float*)d_out;
    float* spect = out;                           // B*NBINS
    float* probs = out + (size_t)B_DIM * NBINS;   // B*S (scores -> probs in place)

    short* wprep = (short*)d_ws;                  // 36*16384 shorts
    short* vertB = wprep + 36 * 16384;            // 16*16384 shorts
    float* maskB = (float*)(vertB + 16 * 16384);  // 384 f32
    int*   eiB   = (int*)(maskB + B_DIM * A_DIM); // 384 int

    k_prep<<<1665, 256, 0, stream>>>(combine_W, l1_W, l2a_W, l2b_W,
        vert_feat, vert_mask, elem_oh, wprep, vertB, maskB, eiB);
    k_mlp<<<1024, 512, 0, stream>>>(subsets, wprep, vertB, maskB, eiB,
        combine_b, l1_b, l2a_b, l2b_b, score_W, score_b, probs);
    k_softmax<<<B_DIM, 256, 0, stream>>>(probs);
    k_zero4<<<(B_DIM * NBINS / 4) / 256, 256, 0, stream>>>(
        (float4*)spect, B_DIM * NBINS / 4);
    k_scatter<<<(B_DIM * S_DIM * P_DIM) / 256, 256, 0, stream>>>(
        mass_idx, intensity, probs, spect);
}

// Round 8
// 246.587 us; speedup vs baseline: 2.0997x; 1.0796x over previous
//
#include <hip/hip_runtime.h>
#include <math.h>

// Problem constants
#define B_DIM 8
#define A_DIM 48
#define GF_DIM 256
#define S_DIM 4096
#define P_DIM 32
#define E_DIM 5
#define OHN 100
#define NBINS 65536

typedef __attribute__((ext_vector_type(8))) short short8v;
typedef __attribute__((ext_vector_type(4))) float float4v;

// ---------------- helpers ----------------
__device__ __forceinline__ float wave_sum(float v) {
#pragma unroll
    for (int o = 32; o; o >>= 1) v += __shfl_xor(v, o, 64);
    return v;
}
__device__ __forceinline__ float wave_max(float v) {
#pragma unroll
    for (int o = 32; o; o >>= 1) v = fmaxf(v, __shfl_xor(v, o, 64));
    return v;
}
__device__ __forceinline__ float quad16_sum(float v) {
    v += __shfl_xor(v, 1, 64); v += __shfl_xor(v, 2, 64);
    v += __shfl_xor(v, 4, 64); v += __shfl_xor(v, 8, 64);
    return v;
}
__device__ __forceinline__ unsigned short bf16_rn(float x) {
    unsigned int u = __float_as_uint(x);
    return (unsigned short)((u + 0x7FFFu + ((u >> 16) & 1u)) >> 16);
}
__device__ __forceinline__ float bf16_val(unsigned short h) {
    return __uint_as_float(((unsigned int)h) << 16);
}
__device__ __forceinline__ float4v mfma_bf16(short8v a, short8v b, float4v c) {
    return __builtin_amdgcn_mfma_f32_16x16x32_bf16(a, b, c, 0, 0, 0);
}

// ---------------- prep: W hi/lo streams + vert*mask^2 + mask/ei + zero spect -
// Blocks 0..1151: MLP W streams (36 chunks x 16384 shorts). Chunk c,
// frag_id = wn*4 + hl*2 + nt; frag 512 shorts: (lane,j) =
// W[k = c_rel*32 + (lane>>4)*8 + j][n = wn*32 + nt*16 + (lane&15)].
// Chunks 0..11 combine (therm k' 0..99, pad 100..127, normed -> 128..383);
// 12..19 l1; 20..27 l2a; 28..35 l2b.
// Blocks 1152..1663: vertB (16 chunks: batch b = vc>>1, v = vc&1,
// val = vert_feat[b][k][n] * mask[b][k]^2, zero-padded k>=48).
// Block 1664: maskB (8x48 f32), eiB (8x48 int) — grid-stride over 384.
// Blocks 1665..2176: zero spect (B*NBINS f32, float4 stores).
__global__ __launch_bounds__(256) void k_prep(
    const float* __restrict__ cW, const float* __restrict__ l1W,
    const float* __restrict__ l2aW, const float* __restrict__ l2bW,
    const float* __restrict__ vert_feat, const float* __restrict__ vert_mask,
    const float* __restrict__ elem_oh,
    short* __restrict__ wp, short* __restrict__ wv,
    float* __restrict__ maskB, int* __restrict__ eiB,
    float4* __restrict__ spect4)
{
    const int blk = blockIdx.x;
    const int tid = threadIdx.x;
    if (blk < 1152) {
        int e = blk * 256 + tid;              // < 36*8192
        int c = e >> 13;
        int i = e & 8191;
        int j    = i & 7;
        int lane = (i >> 3) & 63;
        int nt   = (i >> 9) & 1;
        int wn   = i >> 10;
        int krel = (lane >> 4) * 8 + j;
        int n    = wn * 32 + nt * 16 + (lane & 15);
        float val = 0.f;
        if (c < 12) {
            int kp = c * 32 + krel;
            if (kp < 100)       val = cW[kp * 256 + n];
            else if (kp >= 128) val = cW[(kp - 28) * 256 + n];
        } else {
            int L  = (c - 12) >> 3;
            int kc = (c - 12) & 7;
            const float* W = (L == 0) ? l1W : (L == 1) ? l2aW : l2bW;
            val = W[(kc * 32 + krel) * 256 + n];
        }
        unsigned short h = bf16_rn(val);
        float lo = val - bf16_val(h);
        int base = c * 16384 + (i & 511);
        wp[base + (wn * 4 + nt) * 512]     = (short)h;
        wp[base + (wn * 4 + 2 + nt) * 512] = (short)bf16_rn(lo);
    } else if (blk < 1664) {
        int vb = blk - 1152;
        int vc = vb >> 5;                     // 0..15
        int i  = (vb & 31) * 256 + tid;       // 0..8191
        int b  = vc >> 1, v = vc & 1;
        int j    = i & 7;
        int lane = (i >> 3) & 63;
        int nt   = (i >> 9) & 1;
        int wn   = i >> 10;
        int k = v * 32 + (lane >> 4) * 8 + j;
        int n = wn * 32 + nt * 16 + (lane & 15);
        float val = 0.f;
        if (k < A_DIM) {
            float mk = vert_mask[b * A_DIM + k];
            val = vert_feat[((size_t)(b * A_DIM + k)) * GF_DIM + n] * mk * mk;
        }
        unsigned short h = bf16_rn(val);
        float lo = val - bf16_val(h);
        int base = vc * 16384 + (i & 511);
        wv[base + (wn * 4 + nt) * 512]     = (short)h;
        wv[base + (wn * 4 + 2 + nt) * 512] = (short)bf16_rn(lo);
    } else if (blk == 1664) {
        // grid-stride: 384 entries with 256 threads
        for (int t = tid; t < B_DIM * A_DIM; t += 256) {
            maskB[t] = vert_mask[t];
            int ei = 0;
#pragma unroll
            for (int e = 0; e < E_DIM; ++e)
                if (elem_oh[t * E_DIM + e] > 0.5f) ei = e;
            eiB[t] = ei;
        }
    } else {
        // zero spect: 512 blocks x 256 thr x float4 = 524288 f32
        int z = (blk - 1665) * 256 + tid;
        spect4[z] = make_float4(0.f, 0.f, 0.f, 0.f);
    }
}

// ---------------- MLP kernel: M=32/block, 3 blocks/CU (LDS-limited) ---------
// LDS: xAh 24576 | xAl 16384 | fm 4096 | ps 1024 | cnt 640 | invsz 128
#define L_XAL 24576
#define L_FM  40960
#define L_PS  45056
#define L_CNT 46080
#define L_INV 46720
#define L_TOT 46848

// One GEMM layer, barrier-free K loop; W slice in regs (depth-2 prefetch).
template <int NKC, int LO0, int ACT, bool NORM, bool SCORE>
__device__ __forceinline__ void layer_pass(
    short* xAh, short* xAl, float (*ps)[32],
    const short* __restrict__ wstream, const float* __restrict__ bias,
    const float* __restrict__ sW, const float* __restrict__ sb,
    float* __restrict__ scores, int R0)
{
    const int tid  = threadIdx.x;
    const int lane = tid & 63;
    const int wn   = tid >> 6;
    const int quad = lane >> 4;
    const int col  = lane & 15;
    const short* wbase = wstream + wn * 2048 + lane * 8;

    float4v acc[2][2];
#pragma unroll
    for (int mi = 0; mi < 2; ++mi)
#pragma unroll
        for (int nt = 0; nt < 2; ++nt) acc[mi][nt] = (float4v){0.f, 0.f, 0.f, 0.f};

    short8v bh[3][2], bl[3][2];
#pragma unroll
    for (int p = 0; p < 2; ++p) {
        if (p < NKC) {
            const short* q = wbase + p * 16384;
            bh[p][0] = *(const short8v*)(q);
            bh[p][1] = *(const short8v*)(q + 512);
            bl[p][0] = *(const short8v*)(q + 1024);
            bl[p][1] = *(const short8v*)(q + 1536);
        }
    }

#pragma unroll
    for (int kc = 0; kc < NKC; ++kc) {
        const int cur = kc % 3;
        if (kc + 2 < NKC) {
            const int nxt = (kc + 2) % 3;
            const short* q = wbase + (kc + 2) * 16384;
            bh[nxt][0] = *(const short8v*)(q);
            bh[nxt][1] = *(const short8v*)(q + 512);
            bl[nxt][0] = *(const short8v*)(q + 1024);
            bl[nxt][1] = *(const short8v*)(q + 1536);
        }
        short8v ah[2], al[2];
#pragma unroll
        for (int mi = 0; mi < 2; ++mi)
            ah[mi] = *(const short8v*)(xAh + ((kc * 2 + mi) * 64 + lane) * 8);
        const bool hlo = (kc >= LO0);
        if (hlo) {
#pragma unroll
            for (int mi = 0; mi < 2; ++mi)
                al[mi] = *(const short8v*)(xAl + (((kc - LO0) * 2 + mi) * 64 + lane) * 8);
        }
#pragma unroll
        for (int mi = 0; mi < 2; ++mi)
#pragma unroll
            for (int nt = 0; nt < 2; ++nt) {
                acc[mi][nt] = mfma_bf16(ah[mi], bh[cur][nt], acc[mi][nt]);
                acc[mi][nt] = mfma_bf16(ah[mi], bl[cur][nt], acc[mi][nt]);
                if (hlo)
                    acc[mi][nt] = mfma_bf16(al[mi], bh[cur][nt], acc[mi][nt]);
            }
    }

    // bias + activation
    float bc0 = bias[wn * 32 + col];
    float bc1 = bias[wn * 32 + 16 + col];
#pragma unroll
    for (int mi = 0; mi < 2; ++mi)
#pragma unroll
        for (int r = 0; r < 4; ++r) {
            float z0 = acc[mi][0][r] + bc0;
            float z1 = acc[mi][1][r] + bc1;
            if (ACT == 0) { z0 = fmaxf(z0, 0.f); z1 = fmaxf(z1, 0.f); }
            else { z0 = (z0 > 0.f) ? z0 : 0.01f * z0; z1 = (z1 > 0.f) ? z1 : 0.01f * z1; }
            acc[mi][0][r] = z0; acc[mi][1][r] = z1;
        }

    __syncthreads();   // all xA reads of this layer done

    if (NORM) {
        float rsum[2][4];
#pragma unroll
        for (int mi = 0; mi < 2; ++mi)
#pragma unroll
            for (int r = 0; r < 4; ++r)
                rsum[mi][r] = quad16_sum(acc[mi][0][r] + acc[mi][1][r]);
        if (col == 0) {
#pragma unroll
            for (int mi = 0; mi < 2; ++mi)
#pragma unroll
                for (int r = 0; r < 4; ++r)
                    ps[wn][mi * 16 + quad * 4 + r] = rsum[mi][r];
        }
        __syncthreads();
        float mu[2][4];
#pragma unroll
        for (int mi = 0; mi < 2; ++mi)
#pragma unroll
            for (int r = 0; r < 4; ++r) {
                int m = mi * 16 + quad * 4 + r;
                float s = 0.f;
#pragma unroll
                for (int w = 0; w < 8; ++w) s += ps[w][m];
                mu[mi][r] = s * (1.f / 256.f);
            }
        __syncthreads();
        float qs[2][4];
#pragma unroll
        for (int mi = 0; mi < 2; ++mi)
#pragma unroll
            for (int r = 0; r < 4; ++r) {
                acc[mi][0][r] -= mu[mi][r];
                acc[mi][1][r] -= mu[mi][r];
                float q = acc[mi][0][r] * acc[mi][0][r]
                        + acc[mi][1][r] * acc[mi][1][r];
                qs[mi][r] = quad16_sum(q);
            }
        if (col == 0) {
#pragma unroll
            for (int mi = 0; mi < 2; ++mi)
#pragma unroll
                for (int r = 0; r < 4; ++r)
                    ps[wn][mi * 16 + quad * 4 + r] = qs[mi][r];
        }
        __syncthreads();
#pragma unroll
        for (int mi = 0; mi < 2; ++mi)
#pragma unroll
            for (int r = 0; r < 4; ++r) {
                int m = mi * 16 + quad * 4 + r;
                float s = 0.f;
#pragma unroll
                for (int w = 0; w < 8; ++w) s += ps[w][m];
                float rsf = 1.0f / sqrtf(s * (1.f / 256.f) + 1e-5f);
                acc[mi][0][r] *= rsf;
                acc[mi][1][r] *= rsf;
            }
    }

    if (SCORE) {
        __syncthreads();
        float sv0 = sW[wn * 32 + col];
        float sv1 = sW[wn * 32 + 16 + col];
        float psu[2][4];
#pragma unroll
        for (int mi = 0; mi < 2; ++mi)
#pragma unroll
            for (int r = 0; r < 4; ++r)
                psu[mi][r] = quad16_sum(acc[mi][0][r] * sv0 + acc[mi][1][r] * sv1);
        if (col == 0) {
#pragma unroll
            for (int mi = 0; mi < 2; ++mi)
#pragma unroll
                for (int r = 0; r < 4; ++r)
                    ps[wn][mi * 16 + quad * 4 + r] = psu[mi][r];
        }
        __syncthreads();
        if (tid < 32) {
            float s = sb[0];
#pragma unroll
            for (int w = 0; w < 8; ++w) s += ps[w][tid];
            scores[R0 + tid] = s;
        }
    } else {
        // writeback to next layer's A-frag layout; wave wn owns k-chunk wn.
#pragma unroll
        for (int mi = 0; mi < 2; ++mi)
#pragma unroll
            for (int nt = 0; nt < 2; ++nt) {
                int nn0 = (nt * 16 + col) & ~1;
                int q2  = nn0 >> 3;
                int j0  = nn0 & 7;
#pragma unroll
                for (int r = 0; r < 4; ++r) {
                    float v  = acc[mi][nt][r];
                    float pv = __shfl_xor(v, 1, 64);
                    int m15 = quad * 4 + r;
                    int rowidx = (wn * 2 + mi) * 64 + q2 * 16 + m15;
                    if ((col & 1) == 0) {
                        unsigned int wd = (unsigned int)bf16_rn(v)
                                        | ((unsigned int)bf16_rn(pv) << 16);
                        ((unsigned int*)xAh)[rowidx * 4 + (j0 >> 1)] = wd;
                    } else {
                        float ls = v  - bf16_val(bf16_rn(v));
                        float lp = pv - bf16_val(bf16_rn(pv));
                        unsigned int wd = (unsigned int)bf16_rn(lp)
                                        | ((unsigned int)bf16_rn(ls) << 16);
                        ((unsigned int*)xAl)[rowidx * 4 + (j0 >> 1)] = wd;
                    }
                }
            }
        __syncthreads();
    }
}

// NOTE: launch_bounds (512,4) — (512,6) forced VGPR to 40 and spilled 57 MB
// to scratch per dispatch (R7). At 52 VGPR the HW still runs 3 blocks/CU
// (LDS-limited, 47 KB); the bound is a minimum, not a target.
__global__ __launch_bounds__(512, 4) void k_mlp(
    const int* __restrict__ subsets, const short* __restrict__ wprep,
    const short* __restrict__ vertB,
    const float* __restrict__ maskB, const int* __restrict__ eiB,
    const float* __restrict__ cb,  const float* __restrict__ l1b,
    const float* __restrict__ l2ab, const float* __restrict__ l2bb,
    const float* __restrict__ sW,  const float* __restrict__ sb,
    float* __restrict__ scores)
{
    __shared__ __align__(16) char smem[L_TOT];
    short*  xAh = (short*)smem;
    short*  xAl = (short*)(smem + L_XAL);
    short*  fm  = (short*)(smem + L_FM);
    float (*ps)[32]  = (float(*)[32])(smem + L_PS);
    float (*cnt)[5]  = (float(*)[5])(smem + L_CNT);
    float*  invsz    = (float*)(smem + L_INV);

    const int tid  = threadIdx.x;
    const int lane = tid & 63;
    const int wn   = tid >> 6;
    const int quad = lane >> 4;
    const int col  = lane & 15;
    const int fb   = blockIdx.x;          // 0..1023, 32 rows each
    const int b    = fb >> 7;
    const int R0   = fb * 32;

    // ---- phase A1: subset flags -> exact-bf16 A-frags (K=64, k>=48 zero) ----
    if (tid < 256) {
        int g  = tid;
        int lg = g & 63;
        int t2 = g >> 6;                  // kc*2 + mi
        int kc = t2 >> 1, mi = t2 & 1;
        int m  = mi * 16 + (lg & 15);
        int k0 = kc * 32 + (lg >> 4) * 8;
        const int* srow = subsets + (size_t)(R0 + m) * A_DIM;
        short8v hv;
#pragma unroll
        for (int j = 0; j < 8; ++j) {
            int k = k0 + j;
            hv[j] = (short)((k < A_DIM && srow[k]) ? 0x3F80 : 0);
        }
        *(short8v*)(fm + g * 8) = hv;
    }

    // ---- phase A2: per-row element counts (ballot) + 1/subset_size ----
    {
        const float mymask = (lane < A_DIM) ? maskB[b * A_DIM + lane] : 0.f;
        const int   myei   = (lane < A_DIM) ? eiB[b * A_DIM + lane]   : -1;
#pragma unroll
        for (int i = 0; i < 4; ++i) {
            int r = wn * 4 + i;
            int fl = (lane < A_DIM) ? subsets[(size_t)(R0 + r) * A_DIM + lane] : 0;
            unsigned long long m0 = __ballot(fl != 0 && myei == 0);
            unsigned long long m1 = __ballot(fl != 0 && myei == 1);
            unsigned long long m2 = __ballot(fl != 0 && myei == 2);
            unsigned long long m3 = __ballot(fl != 0 && myei == 3);
            unsigned long long m4 = __ballot(fl != 0 && myei == 4);
            float ssz = wave_sum(fl ? mymask : 0.f) + 1e-4f;
            if (lane == 0) {
                cnt[r][0] = (float)__popcll(m0);
                cnt[r][1] = (float)__popcll(m1);
                cnt[r][2] = (float)__popcll(m2);
                cnt[r][3] = (float)__popcll(m3);
                cnt[r][4] = (float)__popcll(m4);
                invsz[r]  = 1.0f / ssz;
            }
        }
    }
    __syncthreads();

    // ---- layer 0: sws = flags @ (vert*mask^2), /size, inorm -> combine input
    {
        const short* wbase = vertB + b * 32768 + wn * 2048 + lane * 8;
        float4v acc[2][2];
#pragma unroll
        for (int mi = 0; mi < 2; ++mi)
#pragma unroll
            for (int nt = 0; nt < 2; ++nt) acc[mi][nt] = (float4v){0.f, 0.f, 0.f, 0.f};

        short8v bh[2][2], bl[2][2];
#pragma unroll
        for (int kc = 0; kc < 2; ++kc) {
            const short* q = wbase + kc * 16384;
            bh[kc][0] = *(const short8v*)(q);
            bh[kc][1] = *(const short8v*)(q + 512);
            bl[kc][0] = *(const short8v*)(q + 1024);
            bl[kc][1] = *(const short8v*)(q + 1536);
        }
#pragma unroll
        for (int kc = 0; kc < 2; ++kc) {
            short8v a0 = *(const short8v*)(fm + ((kc * 2 + 0) * 64 + lane) * 8);
            short8v a1 = *(const short8v*)(fm + ((kc * 2 + 1) * 64 + lane) * 8);
#pragma unroll
            for (int nt = 0; nt < 2; ++nt) {
                acc[0][nt] = mfma_bf16(a0, bh[kc][nt], acc[0][nt]);
                acc[0][nt] = mfma_bf16(a0, bl[kc][nt], acc[0][nt]);
                acc[1][nt] = mfma_bf16(a1, bh[kc][nt], acc[1][nt]);
                acc[1][nt] = mfma_bf16(a1, bl[kc][nt], acc[1][nt]);
            }
        }

        // mean = sws / subset_size
#pragma unroll
        for (int mi = 0; mi < 2; ++mi)
#pragma unroll
            for (int r = 0; r < 4; ++r) {
                float iv = invsz[mi * 16 + quad * 4 + r];
                acc[mi][0][r] *= iv;
                acc[mi][1][r] *= iv;
            }

        __syncthreads();

        // instance norm over 256 cols
        {
            float rsum[2][4];
#pragma unroll
            for (int mi = 0; mi < 2; ++mi)
#pragma unroll
                for (int r = 0; r < 4; ++r)
                    rsum[mi][r] = quad16_sum(acc[mi][0][r] + acc[mi][1][r]);
            if (col == 0) {
#pragma unroll
                for (int mi = 0; mi < 2; ++mi)
#pragma unroll
                    for (int r = 0; r < 4; ++r)
                        ps[wn][mi * 16 + quad * 4 + r] = rsum[mi][r];
            }
            __syncthreads();
            float mu[2][4];
#pragma unroll
            for (int mi = 0; mi < 2; ++mi)
#pragma unroll
                for (int r = 0; r < 4; ++r) {
                    int m = mi * 16 + quad * 4 + r;
                    float s = 0.f;
#pragma unroll
                    for (int w = 0; w < 8; ++w) s += ps[w][m];
                    mu[mi][r] = s * (1.f / 256.f);
                }
            __syncthreads();
            float qs[2][4];
#pragma unroll
            for (int mi = 0; mi < 2; ++mi)
#pragma unroll
                for (int r = 0; r < 4; ++r) {
                    acc[mi][0][r] -= mu[mi][r];
                    acc[mi][1][r] -= mu[mi][r];
                    float q = acc[mi][0][r] * acc[mi][0][r]
                            + acc[mi][1][r] * acc[mi][1][r];
                    qs[mi][r] = quad16_sum(q);
                }
            if (col == 0) {
#pragma unroll
                for (int mi = 0; mi < 2; ++mi)
#pragma unroll
                    for (int r = 0; r < 4; ++r)
                        ps[wn][mi * 16 + quad * 4 + r] = qs[mi][r];
            }
            __syncthreads();
#pragma unroll
            for (int mi = 0; mi < 2; ++mi)
#pragma unroll
                for (int r = 0; r < 4; ++r) {
                    int m = mi * 16 + quad * 4 + r;
                    float s = 0.f;
#pragma unroll
                    for (int w = 0; w < 8; ++w) s += ps[w][m];
                    float rsf = 1.0f / sqrtf(s * (1.f / 256.f) + 1e-5f);
                    acc[mi][0][r] *= rsf;
                    acc[mi][1][r] *= rsf;
                }
        }

        // writeback: normed cols n -> combine k' = 128+n (xAh kc 4+wn, xAl chunk wn)
#pragma unroll
        for (int mi = 0; mi < 2; ++mi)
#pragma unroll
            for (int nt = 0; nt < 2; ++nt) {
                int nn0 = (nt * 16 + col) & ~1;
                int q2  = nn0 >> 3;
                int j0  = nn0 & 7;
#pragma unroll
                for (int r = 0; r < 4; ++r) {
                    float v  = acc[mi][nt][r];
                    float pv = __shfl_xor(v, 1, 64);
                    int m15 = quad * 4 + r;
                    int rh = ((4 + wn) * 2 + mi) * 64 + q2 * 16 + m15;
                    int rl = (wn * 2 + mi) * 64 + q2 * 16 + m15;
                    if ((col & 1) == 0) {
                        unsigned int wd = (unsigned int)bf16_rn(v)
                                        | ((unsigned int)bf16_rn(pv) << 16);
                        ((unsigned int*)xAh)[rh * 4 + (j0 >> 1)] = wd;
                    } else {
                        float ls = v  - bf16_val(bf16_rn(v));
                        float lp = pv - bf16_val(bf16_rn(pv));
                        unsigned int wd = (unsigned int)bf16_rn(lp)
                                        | ((unsigned int)bf16_rn(ls) << 16);
                        ((unsigned int*)xAl)[rl * 4 + (j0 >> 1)] = wd;
                    }
                }
            }

        // thermometer frags into xAh kc 0..3 (512 groups == 512 threads)
        {
            int g  = tid;
            int lg = g & 63;
            int t2 = g >> 6;                 // kc*2 + mi, kc 0..3
            int kc = t2 >> 1, mi = t2 & 1;
            int m  = mi * 16 + (lg & 15);
            int kb = (lg >> 4) * 8;
            float c0 = cnt[m][0], c1 = cnt[m][1], c2 = cnt[m][2],
                  c3 = cnt[m][3], c4 = cnt[m][4];
            short8v hv;
#pragma unroll
            for (int j = 0; j < 8; ++j) {
                int kp = kc * 32 + kb + j;
                float val = 0.f;
                if (kp < 100) {
                    int e = kp / 20;
                    float ce = (e == 0) ? c0 : (e == 1) ? c1 : (e == 2) ? c2
                             : (e == 3) ? c3 : c4;
                    val = ((float)(kp - e * 20) < ce) ? 1.0f : 0.0f;
                }
                hv[j] = (short)((val != 0.f) ? 0x3F80 : 0);
            }
            *(short8v*)(xAh + g * 8) = hv;
        }
        __syncthreads();
    }

    // ---- layers 1..4 ----
    layer_pass<12, 4, 0, true,  false>(xAh, xAl, ps, wprep,
        cb, nullptr, nullptr, nullptr, R0);
    layer_pass< 8, 0, 0, false, false>(xAh, xAl, ps, wprep + 12 * 16384,
        l1b, nullptr, nullptr, nullptr, R0);
    layer_pass< 8, 0, 1, false, false>(xAh, xAl, ps, wprep + 20 * 16384,
        l2ab, nullptr, nullptr, nullptr, R0);
    layer_pass< 8, 0, 0, true,  true >(xAh, xAl, ps, wprep + 28 * 16384,
        l2bb, sW, sb, scores, R0);
}

// ---------------- softmax / scatter ----------------
__global__ __launch_bounds__(256) void k_softmax(float* __restrict__ probs) {
    const int b   = blockIdx.x;
    const int tid = threadIdx.x;
    __shared__ float redA[4];
    __shared__ float redB[4];
    float* sp = probs + (size_t)b * S_DIM;

    float v[16];
    float mx = -INFINITY;
#pragma unroll
    for (int i = 0; i < 16; ++i) {
        v[i] = sp[tid + i * 256];
        mx = fmaxf(mx, v[i]);
    }
    mx = wave_max(mx);
    if ((tid & 63) == 0) redA[tid >> 6] = mx;
    __syncthreads();
    mx = fmaxf(fmaxf(redA[0], redA[1]), fmaxf(redA[2], redA[3]));

    float sum = 0.f;
#pragma unroll
    for (int i = 0; i < 16; ++i) {
        v[i] = expf(v[i] - mx);
        sum += v[i];
    }
    sum = wave_sum(sum);
    if ((tid & 63) == 0) redB[tid >> 6] = sum;
    __syncthreads();
    float tot = redB[0] + redB[1] + redB[2] + redB[3];
    float inv = 1.0f / tot;
#pragma unroll
    for (int i = 0; i < 16; ++i) sp[tid + i * 256] = v[i] * inv;
}

__global__ __launch_bounds__(256) void k_scatter(
    const int*   __restrict__ mass_idx,
    const float* __restrict__ intensity,
    const float* __restrict__ probs,
    float* __restrict__ spect)
{
    int i  = blockIdx.x * 256 + threadIdx.x;
    int bs = i >> 5;
    int b  = i >> 17;
    float w = intensity[i] * probs[bs];
    unsafeAtomicAdd(spect + ((size_t)b << 16) + mass_idx[i], w);
}

// ---------------- launch ----------------
extern "C" void kernel_launch(void* const* d_in, const int* in_sizes, int n_in,
                              void* d_out, int out_size, void* d_ws, size_t ws_size,
                              hipStream_t stream) {
    const float* vert_feat = (const float*)d_in[0];
    const float* vert_mask = (const float*)d_in[1];
    const float* elem_oh   = (const float*)d_in[2];
    const int*   subsets   = (const int*)d_in[4];
    const int*   mass_idx  = (const int*)d_in[6];
    const float* intensity = (const float*)d_in[7];
    const float* combine_W = (const float*)d_in[8];
    const float* combine_b = (const float*)d_in[9];
    const float* l1_W      = (const float*)d_in[10];
    const float* l1_b      = (const float*)d_in[11];
    const float* l2a_W     = (const float*)d_in[12];
    const float* l2a_b     = (const float*)d_in[13];
    const float* l2b_W     = (const float*)d_in[14];
    const float* l2b_b     = (const float*)d_in[15];
    const float* score_W   = (const float*)d_in[16];
    const float* score_b   = (const float*)d_in[17];

    float* out   = (float*)d_out;
    float* spect = out;                           // B*NBINS
    float* probs = out + (size_t)B_DIM * NBINS;   // B*S (scores -> probs in place)

    short* wprep = (short*)d_ws;                  // 36*16384 shorts
    short* vertB = wprep + 36 * 16384;            // 16*16384 shorts
    float* maskB = (float*)(vertB + 16 * 16384);  // 384 f32
    int*   eiB   = (int*)(maskB + B_DIM * A_DIM); // 384 int

    k_prep<<<2177, 256, 0, stream>>>(combine_W, l1_W, l2a_W, l2b_W,
        vert_feat, vert_mask, elem_oh, wprep, vertB, maskB, eiB,
        (float4*)spect);
    k_mlp<<<1024, 512, 0, stream>>>(subsets, wprep, vertB, maskB, eiB,
        combine_b, l1_b, l2a_b, l2b_b, score_W, score_b, probs);
    k_softmax<<<B_DIM, 256, 0, stream>>>(probs);
    k_scatter<<<(B_DIM * S_DIM * P_DIM) / 256, 256, 0, stream>>>(
        mass_idx, intensity, probs, spect);
}